// Round 6
// baseline (363.743 us; speedup 1.0000x reference)
//
#include <hip/hip_runtime.h>
#include <stdint.h>

// Problem constants
#define B_SZ   32
#define N_TOK  1024
#define C_DIM  768
#define HEADS  8
#define CH_DIM 96
#define GM     32768          // B*N rows
#define GN     2304           // 3*C cols
#define GK     768            // K
#define SCALE_F 0.10206207261596577f   // 96^-0.5

typedef __attribute__((ext_vector_type(8))) short short8;
typedef __attribute__((ext_vector_type(8))) unsigned short ushort8;
typedef __attribute__((ext_vector_type(4))) float f32x4;

__device__ __forceinline__ float bf2f(unsigned short u) {
  union { unsigned int i; float f; } x; x.i = ((unsigned int)u) << 16; return x.f;
}
__device__ __forceinline__ unsigned short f2bf(float f) {
  union { float f; unsigned int i; } x; x.f = f;
  unsigned int r = x.i + 0x7fffu + ((x.i >> 16) & 1u);
  return (unsigned short)(r >> 16);
}

// async global->LDS, 16B/lane. LDS dest must be WAVE-UNIFORM; HW adds lane*16.
__device__ __forceinline__ void gload_lds16(const void* g, void* l) {
  __builtin_amdgcn_global_load_lds(
      (const __attribute__((address_space(1))) unsigned int*)g,
      (__attribute__((address_space(3))) unsigned int*)l, 16, 0, 0);
}

// ---------------- fp32 -> bf16 convert (both inputs, one launch) ---------------
#define NX4 (GM * GK / 4)
#define NW4 (GN * GK / 4)
__global__ void f32_to_bf16_all(const float4* __restrict__ x, ushort4* __restrict__ xb,
                                const float4* __restrict__ wq, ushort4* __restrict__ wbo) {
  int i = blockIdx.x * 256 + threadIdx.x;
  const float4* src; ushort4* dst; int j;
  if (i < NX4) { src = x; dst = xb; j = i; }
  else { j = i - NX4; if (j >= NW4) return; src = wq; dst = wbo; }
  float4 v = src[j];
  ushort4 o;
  o.x = f2bf(v.x); o.y = f2bf(v.y); o.z = f2bf(v.z); o.w = f2bf(v.w);
  dst[j] = o;
}

// ---------------- qkv GEMM, 8-phase schedule (m201 port) -----------------------
// 256x256 tile, BK=64, 8 waves (2M x 4N), per-wave out 128x64 (acc[8][4]).
// LDS [2 dbuf][A|B][256 rows x 128B], rows PERMUTED so each phase's stage-unit
// is 128 contiguous rows:  A: lrow = mq*128 + wr*64 + r6 (grow = wr*128+mq*64+r6)
//                          B: lrow = nh*128 + wc*32 + r5 (grow = wc*64+nh*32+r5)
// Swizzle byte ^= (row&7)<<4 : read-side XOR == stage-source pre-XOR (involution).
// Per K-tile: 4 phases {reads | stage 1 unit | bar | lgkm0 | prio1 16xMFMA prio0 | bar},
// vmcnt(6) once per K-tile at P3 (2 loads/unit x 3 units in flight).
#define SB __builtin_amdgcn_sched_barrier(0)
#define PHW do { SB; __builtin_amdgcn_s_barrier();                      \
    asm volatile("s_waitcnt lgkmcnt(0)" ::: "memory"); SB; } while (0)
#define PHE do { SB; __builtin_amdgcn_s_barrier(); SB; } while (0)

#define R_A(MQ) do {                                                               \
    const char* _b = &lds[db][0][(size_t)(((MQ)*128) + wr*64 + l15) * 128];        \
    Af[0][0]=*(const short8*)(_b+0*2048+ck0); Af[0][1]=*(const short8*)(_b+0*2048+ck1); \
    Af[1][0]=*(const short8*)(_b+1*2048+ck0); Af[1][1]=*(const short8*)(_b+1*2048+ck1); \
    Af[2][0]=*(const short8*)(_b+2*2048+ck0); Af[2][1]=*(const short8*)(_b+2*2048+ck1); \
    Af[3][0]=*(const short8*)(_b+3*2048+ck0); Af[3][1]=*(const short8*)(_b+3*2048+ck1); \
  } while (0)

#define R_B(NH) do {                                                               \
    const char* _b = &lds[db][1][(size_t)(((NH)*128) + wc*32 + l15) * 128];        \
    Bf[NH][0][0]=*(const short8*)(_b+ck0);      Bf[NH][0][1]=*(const short8*)(_b+ck1);      \
    Bf[NH][1][0]=*(const short8*)(_b+2048+ck0); Bf[NH][1][1]=*(const short8*)(_b+2048+ck1); \
  } while (0)

#define MFMA16(MQ, NH) do {                                                        \
    __builtin_amdgcn_s_setprio(1);                                                 \
    _Pragma("unroll") for (int ks = 0; ks < 2; ++ks)                               \
      _Pragma("unroll") for (int mf = 0; mf < 4; ++mf)                             \
        _Pragma("unroll") for (int nf = 0; nf < 2; ++nf)                           \
          acc[(MQ)*4+mf][(NH)*2+nf] = __builtin_amdgcn_mfma_f32_16x16x32_bf16(     \
              Af[mf][ks], Bf[NH][nf][ks], acc[(MQ)*4+mf][(NH)*2+nf], 0, 0, 0);     \
    __builtin_amdgcn_s_setprio(0);                                                 \
  } while (0)

__global__ __launch_bounds__(512, 2) void qkv_gemm8(
    const unsigned short* __restrict__ xb,   // [GM][768] bf16
    const unsigned short* __restrict__ wb,   // [GN][768] bf16 (B^T layout)
    unsigned short* __restrict__ qkv) {      // [GM][GN] bf16
  __shared__ __align__(16) char lds[2][2][32768];   // 128 KB

  const int t = threadIdx.x, w = t >> 6, l = t & 63;
  const int l15 = l & 15, lhi = l >> 4;
  const int bid = blockIdx.x;
  const int swz = (bid & 7) * 144 + (bid >> 3);     // bijective XCD swizzle (1152%8==0)
  const int brow = (swz / 9) * 256;
  const int bcol = (swz % 9) * 256;
  const int wr = w >> 2, wc = w & 3;

  // read-side swizzled chunk offsets (bytes): chunk = (ks*4+lhi) ^ (l15&7)
  const int ck0 = ((lhi)     ^ (l15 & 7)) << 4;
  const int ck1 = ((lhi + 4) ^ (l15 & 7)) << 4;
  // stage-source pre-swizzle: lane l -> dest row+=(l>>3), granule l&7
  const int sch = (((l & 7) ^ ((l >> 3) & 7)) << 4);
  const int rll = w * 8 + (l >> 3);                 // lane's LDS row within a unit-op

  auto STAGE_A = [&](int db_, int kt_, int mq_) {
#pragma unroll
    for (int op = 0; op < 2; ++op) {
      const int rl = mq_ * 128 + op * 64 + rll;
      const int grow = ((rl >> 6) & 1) * 128 + (rl >> 7) * 64 + (rl & 63);
      gload_lds16((const char*)xb + (size_t)(brow + grow) * 1536 + kt_ * 128 + sch,
                  &lds[db_][0][(size_t)(mq_ * 128 + op * 64 + w * 8) * 128]);
    }
  };
  auto STAGE_B = [&](int db_, int kt_, int nh_) {
#pragma unroll
    for (int op = 0; op < 2; ++op) {
      const int rl = nh_ * 128 + op * 64 + rll;
      const int grow = ((rl >> 5) & 3) * 64 + (rl >> 7) * 32 + (rl & 31);
      gload_lds16((const char*)wb + (size_t)(bcol + grow) * 1536 + kt_ * 128 + sch,
                  &lds[db_][1][(size_t)(nh_ * 128 + op * 64 + w * 8) * 128]);
    }
  };

  f32x4 acc[8][4];
#pragma unroll
  for (int m = 0; m < 8; ++m)
#pragma unroll
    for (int n = 0; n < 4; ++n) acc[m][n] = (f32x4){0.f, 0.f, 0.f, 0.f};
  short8 Af[4][2], Bf[2][2][2];

  // prologue: stage all of kt=0 (4 units) + 3 units of kt=1; wait first 4.
  STAGE_A(0, 0, 0); STAGE_B(0, 0, 0); STAGE_B(0, 0, 1); STAGE_A(0, 0, 1);
  STAGE_A(1, 1, 0); STAGE_B(1, 1, 0); STAGE_B(1, 1, 1);
  SB; asm volatile("s_waitcnt vmcnt(6)" ::: "memory"); SB;
  __builtin_amdgcn_s_barrier(); SB;

  for (int kt = 0; kt < 12; ++kt) {
    const int db = kt & 1;
    // ---- P0: quadrant (mq0, nh0)
    R_B(0); R_A(0);
    if (kt < 11) STAGE_A(db ^ 1, kt + 1, 1);       // Am1(kt+1)
    PHW; MFMA16(0, 0); PHE;
    // ---- P1: (mq0, nh1)
    R_B(1);
    if (kt < 10) STAGE_A(db, kt + 2, 0);           // Am0(kt+2)
    PHW; MFMA16(0, 1); PHE;
    // ---- P2: (mq1, nh1)
    R_A(1);
    if (kt < 10) STAGE_B(db, kt + 2, 0);           // Bn0(kt+2)
    PHW; MFMA16(1, 1); PHE;
    // ---- P3: (mq1, nh0) + counted vmcnt for kt+1's data
    if (kt < 10) {
      STAGE_B(db, kt + 2, 1);                      // Bn1(kt+2)
      SB; asm volatile("s_waitcnt vmcnt(6)" ::: "memory");
    } else if (kt == 10) {
      SB; asm volatile("s_waitcnt vmcnt(0)" ::: "memory");
    }
    PHW; MFMA16(1, 0); PHE;
  }

  // epilogue: C/D layout col=lane&15, row=(lane>>4)*4+reg
#pragma unroll
  for (int m = 0; m < 8; ++m) {
    const int row0 = brow + wr * 128 + m * 16 + lhi * 4;
#pragma unroll
    for (int n = 0; n < 4; ++n) {
      const int col = bcol + wc * 64 + n * 16 + l15;
#pragma unroll
      for (int r = 0; r < 4; ++r)
        qkv[(size_t)(row0 + r) * GN + col] = f2bf(acc[m][n][r]);
    }
  }
}

// ---------------- dd^T = (softmax(k)^T @ v)^T per (b,h), fused normalize -------
// softmax(k) = exp(k)/colsum(exp k); colsum via all-ones B-fragment MFMA.
// Cross-wave combine via concurrent LDS float atomics (ds_add_f32).
__global__ __launch_bounds__(512, 2) void dd_fused(
    const unsigned short* __restrict__ qkv,
    unsigned short* __restrict__ ddT) {
  __shared__ __align__(16) char smem[123648];
  unsigned short* stg = (unsigned short*)smem;          // [8 waves][2][96*40]
  float* facc = (float*)smem;                           // alias: [96][100] fp32
  float* fsum = (float*)(smem + 122880);                // [96] colsum
  float* sinv = (float*)(smem + 123264);                // [96]

  const int bh = blockIdx.x, b = bh >> 3, h = bh & 7;
  const int t = threadIdx.x, w = t >> 6, l = t & 63;
  const int l15 = l & 15, lhi = l >> 4;

  unsigned short* myK = stg + w * 7680;
  unsigned short* myV = myK + 3840;
  const int n   = l >> 1;
  const int chh = l & 1;
  const size_t baseK = (size_t)b * N_TOK * GN + 768  + h * 96;
  const size_t baseV = baseK + 768;

  f32x4 acc[6][6], accS[6];
#pragma unroll
  for (int mf = 0; mf < 6; ++mf) {
    accS[mf] = (f32x4){0.f, 0.f, 0.f, 0.f};
#pragma unroll
    for (int nf = 0; nf < 6; ++nf) acc[mf][nf] = (f32x4){0.f, 0.f, 0.f, 0.f};
  }
  short8 ones;
#pragma unroll
  for (int j = 0; j < 8; ++j) ones[j] = (short)0x3F80;   // bf16 1.0

  for (int tt = 0; tt < 4; ++tt) {
    const int n0 = w * 128 + tt * 32;
    const size_t gk = baseK + (size_t)(n0 + n) * GN + chh * 48;
    const size_t gv = baseV + (size_t)(n0 + n) * GN + chh * 48;
#pragma unroll
    for (int i = 0; i < 6; ++i) {
      ushort8 k8 = *(const ushort8*)(qkv + gk + i * 8);
      ushort8 v8 = *(const ushort8*)(qkv + gv + i * 8);
      const int c0 = chh * 48 + i * 8;
#pragma unroll
      for (int j = 0; j < 8; ++j) {
        float e = __expf(bf2f(k8[j]));
        myK[(c0 + j) * 40 + n] = f2bf(e);
        myV[(c0 + j) * 40 + n] = v8[j];
      }
    }
    // same-wave DS ordering: compiler waits lgkmcnt before dependent reads
    short8 af[6], bf8[6];
#pragma unroll
    for (int mf = 0; mf < 6; ++mf)
      af[mf] = *(const short8*)((const char*)myK + (mf * 16 + l15) * 80 + lhi * 16);
#pragma unroll
    for (int nf = 0; nf < 6; ++nf)
      bf8[nf] = *(const short8*)((const char*)myV + (nf * 16 + l15) * 80 + lhi * 16);
#pragma unroll
    for (int mf = 0; mf < 6; ++mf) {
#pragma unroll
      for (int nf = 0; nf < 6; ++nf)
        acc[mf][nf] = __builtin_amdgcn_mfma_f32_16x16x32_bf16(af[mf], bf8[nf], acc[mf][nf], 0, 0, 0);
      accS[mf] = __builtin_amdgcn_mfma_f32_16x16x32_bf16(af[mf], ones, accS[mf], 0, 0, 0);
    }
  }

  __syncthreads();   // staging dead; facc aliases it
  for (int i = t; i < 9600; i += 512) facc[i] = 0.f;
  if (t < 96) fsum[t] = 0.f;
  __syncthreads();

#pragma unroll
  for (int mf = 0; mf < 6; ++mf) {
#pragma unroll
    for (int nf = 0; nf < 6; ++nf) {
      const int c = mf * 16 + lhi * 4, d = nf * 16 + l15;
#pragma unroll
      for (int r = 0; r < 4; ++r)
        atomicAdd(&facc[(size_t)(c + r) * 100 + d], acc[mf][nf][r]);
    }
    if (l15 == 0) {
      const int c = mf * 16 + lhi * 4;
#pragma unroll
      for (int r = 0; r < 4; ++r) atomicAdd(&fsum[c + r], accS[mf][r]);
    }
  }
  __syncthreads();
  if (t < 96) sinv[t] = 1.0f / fsum[t];
  __syncthreads();

  unsigned short* dst = ddT + (size_t)bh * 9216;
#pragma unroll
  for (int e = 0; e < 18; ++e) {
    const int idx = t * 18 + e;
    const int d = idx / 96, c = idx % 96;
    dst[idx] = f2bf(facc[(size_t)c * 100 + d] * sinv[c]);
  }
}

// ---------------- out = SCALE*(q@dd) + q*dwconv3x3(v), conv fused --------------
// grid (16 nt, 8 h, 32 b), 256 thr, 4 waves 2x2 of (32 rows x 48 cols).
__global__ __launch_bounds__(256) void factor_conv_mfma(
    const unsigned short* __restrict__ qkv,
    const unsigned short* __restrict__ ddT,    // [bh][96 d][96 c] bf16
    const float* __restrict__ wcr,             // [768][9]
    const float* __restrict__ bcr,             // [768]
    float* __restrict__ outb) {
  __shared__ __align__(16) unsigned short sQ[64 * 96];    // 12288 B
  __shared__ __align__(16) unsigned short sD[96 * 96];    // 18432 B
  __shared__ __align__(16) unsigned short sV[128 * 96];   // 24576 B (v halo: 4 img rows)
  __shared__ float sW[96 * 9];
  __shared__ float sBias[96];
  const int nt = blockIdx.x, h = blockIdx.y, b = blockIdx.z;
  const int t = threadIdx.x, wv = t >> 6, l = t & 63;
  const int l15 = l & 15, lhi = l >> 4;
  const int bh = b * 8 + h;
  const int n0 = nt * 64, y0 = nt * 2;

  const char* qg = (const char*)qkv + ((size_t)(b * N_TOK + n0)) * (GN * 2) + h * 192;
#pragma unroll
  for (int it = 0; it < 3; ++it) {
    const int f = it * 256 + t;
    const int row = f / 12, ch = f % 12;
    gload_lds16(qg + (size_t)row * (GN * 2) + ch * 16, (char*)sQ + it * 4096 + wv * 1024);
  }
  const char* vg = (const char*)qkv + ((size_t)b * N_TOK) * (GN * 2) + 3072 + h * 192;
#pragma unroll
  for (int it = 0; it < 6; ++it) {
    const int f = it * 256 + t;
    const int row = f / 12, ch = f % 12;
    int tok = n0 - 32 + row;
    tok = tok < 0 ? 0 : (tok > 1023 ? 1023 : tok);
    gload_lds16(vg + (size_t)tok * (GN * 2) + ch * 16, (char*)sV + it * 4096 + wv * 1024);
  }
  const char* dg = (const char*)ddT + (size_t)bh * 18432;
#pragma unroll
  for (int it = 0; it < 4; ++it)
    gload_lds16(dg + (it * 256 + t) * 16, (char*)sD + it * 4096 + wv * 1024);
  if (wv < 2)
    gload_lds16(dg + (1024 + t) * 16, (char*)sD + 16384 + wv * 1024);
  for (int i = t; i < 960; i += 256) {
    if (i < 864) sW[i] = wcr[(size_t)(h * 96) * 9 + i];
    else         sBias[i - 864] = bcr[h * 96 + (i - 864)];
  }
  __syncthreads();

  const int wrow = (wv >> 1) * 32;
  const int wcol = (wv & 1) * 48;
  f32x4 acc[2][3];
#pragma unroll
  for (int m = 0; m < 2; ++m)
#pragma unroll
    for (int nn = 0; nn < 3; ++nn) acc[m][nn] = (f32x4){0.f, 0.f, 0.f, 0.f};

#pragma unroll
  for (int ks = 0; ks < 3; ++ks) {
    short8 af[2], bf8[3];
#pragma unroll
    for (int m = 0; m < 2; ++m)
      af[m] = *(const short8*)((const char*)sQ + (wrow + m*16 + l15) * 192 + ks * 64 + lhi * 16);
#pragma unroll
    for (int nn = 0; nn < 3; ++nn)
      bf8[nn] = *(const short8*)((const char*)sD + (wcol + nn*16 + l15) * 192 + ks * 64 + lhi * 16);
#pragma unroll
    for (int m = 0; m < 2; ++m)
#pragma unroll
      for (int nn = 0; nn < 3; ++nn)
        acc[m][nn] = __builtin_amdgcn_mfma_f32_16x16x32_bf16(af[m], bf8[nn], acc[m][nn], 0, 0, 0);
  }

#pragma unroll
  for (int nn = 0; nn < 3; ++nn) {
    const int dc = wcol + nn * 16 + l15;
    float w9[9];
#pragma unroll
    for (int k = 0; k < 9; ++k) w9[k] = sW[dc * 9 + k];
    const float bv = sBias[dc];
#pragma unroll
    for (int m = 0; m < 2; ++m) {
      const int rl0 = wrow + m * 16 + lhi * 4;
      const int x = rl0 & 31, yl = rl0 >> 5;
      float cs[3][6];
#pragma unroll
      for (int dy = 0; dy < 3; ++dy) {
        const int gy = y0 + yl + dy - 1;
        const bool vy = (gy >= 0) && (gy < 32);
#pragma unroll
        for (int i = 0; i < 6; ++i) {
          const int xx = x - 1 + i;
          cs[dy][i] = (vy && xx >= 0 && xx < 32)
              ? bf2f(sV[((yl + dy) * 32 + xx) * 96 + dc]) : 0.f;
        }
      }
#pragma unroll
      for (int r = 0; r < 4; ++r) {
        float conv = bv;
#pragma unroll
        for (int dy = 0; dy < 3; ++dy)
#pragma unroll
          for (int dx = 0; dx < 3; ++dx)
            conv += w9[dy * 3 + dx] * cs[dy][r + dx];
        const int row = rl0 + r;
        const float qv = bf2f(sQ[row * 96 + dc]);
        outb[((size_t)(b * N_TOK + n0 + row)) * C_DIM + h * 96 + dc] =
            SCALE_F * acc[m][nn][r] + qv * conv;
      }
    }
  }
}

extern "C" void kernel_launch(void* const* d_in, const int* in_sizes, int n_in,
                              void* d_out, int out_size, void* d_ws, size_t ws_size,
                              hipStream_t stream) {
  const float* x      = (const float*)d_in[0];
  const float* w_qkv  = (const float*)d_in[1];
  const float* w_crpe = (const float*)d_in[2];
  const float* b_crpe = (const float*)d_in[3];
  float* out = (float*)d_out;

  char* ws = (char*)d_ws;
  unsigned short* xb    = (unsigned short*)ws;                          // 48 MB
  unsigned short* wb    = (unsigned short*)(ws + 50331648);             // 3.4 MB
  unsigned short* qkv   = (unsigned short*)(ws + 50331648 + 3538944);   // 144 MB
  unsigned short* ddT   = (unsigned short*)(ws + 204865536);            // 4.7 MB bf16

  f32_to_bf16_all<<<dim3((NX4 + NW4 + 255) / 256), 256, 0, stream>>>(
      (const float4*)x, (ushort4*)xb, (const float4*)w_qkv, (ushort4*)wb);
  qkv_gemm8<<<dim3(1152), 512, 0, stream>>>(xb, wb, qkv);
  dd_fused<<<dim3(B_SZ * HEADS), 512, 0, stream>>>(qkv, ddT);
  factor_conv_mfma<<<dim3(16, HEADS, B_SZ), 256, 0, stream>>>(qkv, ddT, w_crpe, b_crpe, out);
}

// Round 7
// 297.052 us; speedup vs baseline: 1.2245x; 1.2245x over previous
//
#include <hip/hip_runtime.h>
#include <stdint.h>

// Problem constants
#define B_SZ   32
#define N_TOK  1024
#define C_DIM  768
#define HEADS  8
#define CH_DIM 96
#define GM     32768          // B*N rows
#define GN     2304           // 3*C cols
#define GK     768            // K
#define SCALE_F 0.10206207261596577f   // 96^-0.5

typedef __attribute__((ext_vector_type(8))) short short8;
typedef __attribute__((ext_vector_type(8))) unsigned short ushort8;
typedef __attribute__((ext_vector_type(4))) float f32x4;

__device__ __forceinline__ float bf2f(unsigned short u) {
  union { unsigned int i; float f; } x; x.i = ((unsigned int)u) << 16; return x.f;
}
__device__ __forceinline__ unsigned short f2bf(float f) {
  union { float f; unsigned int i; } x; x.f = f;
  unsigned int r = x.i + 0x7fffu + ((x.i >> 16) & 1u);
  return (unsigned short)(r >> 16);
}

// async global->LDS, 16B/lane. LDS dest must be WAVE-UNIFORM; HW adds lane*16.
__device__ __forceinline__ void gload_lds16(const void* g, void* l) {
  __builtin_amdgcn_global_load_lds(
      (const __attribute__((address_space(1))) unsigned int*)g,
      (__attribute__((address_space(3))) unsigned int*)l, 16, 0, 0);
}

// ---------------- fp32 -> bf16 convert (both inputs, one launch) ---------------
#define NX4 (GM * GK / 4)
#define NW4 (GN * GK / 4)
__global__ void f32_to_bf16_all(const float4* __restrict__ x, ushort4* __restrict__ xb,
                                const float4* __restrict__ wq, ushort4* __restrict__ wbo) {
  int i = blockIdx.x * 256 + threadIdx.x;
  const float4* src; ushort4* dst; int j;
  if (i < NX4) { src = x; dst = xb; j = i; }
  else { j = i - NX4; if (j >= NW4) return; src = wq; dst = wbo; }
  float4 v = src[j];
  ushort4 o;
  o.x = f2bf(v.x); o.y = f2bf(v.y); o.z = f2bf(v.z); o.w = f2bf(v.w);
  dst[j] = o;
}

// ---------------- qkv GEMM, pipelined: 256x256 tile, BK=32, 4 LDS buffers ------
// 8 waves (2Mx4N), per-wave output 128x64 (acc[8][4]). Counted vmcnt(8).
// LDS swizzle: slot ^= (row>>1)&3 on BOTH stage-source and ds_read (verified:
// SQ_LDS_BANK_CONFLICT == 0 in round 5).
__global__ __launch_bounds__(512, 2) void qkv_gemm_p(
    const unsigned short* __restrict__ xb,   // [GM][768] bf16
    const unsigned short* __restrict__ wb,   // [GN][768] bf16 (B^T layout)
    unsigned short* __restrict__ qkv) {      // [GM][GN] bf16
  __shared__ __align__(16) char lds[4][2][16384];   // [buf][A|B][256 rows x 64B]

  const int t = threadIdx.x, w = t >> 6, l = t & 63;
  const int l15 = l & 15, lhi = l >> 4;

  // XCD-aware bijective swizzle: nwg = 1152 = 8 * 144
  const int bid = blockIdx.x;
  const int swz = (bid & 7) * 144 + (bid >> 3);
  const int brow = (swz / 9) * 256;
  const int bcol = (swz % 9) * 256;
  const int wr = w >> 2, wc = w & 3;

  // staging source pre-swizzle: dst slot = l&3, local row = l>>2, (row>>1)&3 = (l>>3)&3
  const int s_colb = (((l & 3) ^ ((l >> 3) & 3)) << 4);
  const char* gA0 = (const char*)xb + (size_t)brow * 1536 + s_colb;
  const char* gB0 = (const char*)wb + (size_t)bcol * 1536 + s_colb;

  // frag read: row = base16 + l15 -> (row>>1)&3 = (l15>>1)&3
  const int rd_sw = (lhi * 16) ^ (((l15 >> 1) & 3) << 4);
  const int a_off = (wr * 128 + l15) * 64 + rd_sw;
  const int b_off = (wc * 64 + l15) * 64 + rd_sw;

  f32x4 acc[8][4];
#pragma unroll
  for (int m = 0; m < 8; ++m)
#pragma unroll
    for (int n = 0; n < 4; ++n) acc[m][n] = (f32x4){0.f, 0.f, 0.f, 0.f};

  auto STAGE = [&](int bi, int kt) {
#pragma unroll
    for (int rr = 0; rr < 2; ++rr) {
      const int rowA = (w + rr * 8) * 16 + (l >> 2);
      gload_lds16(gA0 + (size_t)rowA * 1536 + kt * 64,
                  &lds[bi][0][(w + rr * 8) * 1024]);
      gload_lds16(gB0 + (size_t)rowA * 1536 + kt * 64,
                  &lds[bi][1][(w + rr * 8) * 1024]);
    }
  };

  auto COMPUTE = [&](int bi) {
    short8 af[8], bf8[4];
#pragma unroll
    for (int n = 0; n < 4; ++n)
      bf8[n] = *(const short8*)(&lds[bi][1][b_off + n * 1024]);
#pragma unroll
    for (int m = 0; m < 8; ++m)
      af[m] = *(const short8*)(&lds[bi][0][a_off + m * 1024]);
    __builtin_amdgcn_s_setprio(1);
#pragma unroll
    for (int m = 0; m < 8; ++m)
#pragma unroll
      for (int n = 0; n < 4; ++n)
        acc[m][n] = __builtin_amdgcn_mfma_f32_16x16x32_bf16(af[m], bf8[n], acc[m][n], 0, 0, 0);
    __builtin_amdgcn_s_setprio(0);
  };

#define BARSYNC_VM(n) do {                                  \
    __builtin_amdgcn_sched_barrier(0);                      \
    asm volatile("s_waitcnt vmcnt(" #n ")" ::: "memory");   \
    __builtin_amdgcn_sched_barrier(0);                      \
    __builtin_amdgcn_s_barrier();                           \
    __builtin_amdgcn_sched_barrier(0);                      \
  } while (0)

  // prologue: 3 K-tiles in flight
  STAGE(0, 0); STAGE(1, 1); STAGE(2, 2);
  BARSYNC_VM(8);   // tile 0 landed (8 = tiles 1,2 outstanding)

  for (int kt = 0; kt < 21; ++kt) {
    STAGE((kt + 3) & 3, kt + 3);
    COMPUTE(kt & 3);
    BARSYNC_VM(8);
  }
  COMPUTE(1); BARSYNC_VM(4);
  COMPUTE(2); BARSYNC_VM(0);
  COMPUTE(3);

  // epilogue: C/D layout col=lane&15, row=(lane>>4)*4+reg
#pragma unroll
  for (int m = 0; m < 8; ++m) {
    const int row0 = brow + wr * 128 + m * 16 + lhi * 4;
#pragma unroll
    for (int n = 0; n < 4; ++n) {
      const int col = bcol + wc * 64 + n * 16 + l15;
#pragma unroll
      for (int r = 0; r < 4; ++r)
        qkv[(size_t)(row0 + r) * GN + col] = f2bf(acc[m][n][r]);
    }
  }
#undef BARSYNC_VM
}

// ---------------- dd^T = (softmax(k)^T @ v)^T per (b,h), fused normalize -------
// softmax(k) = exp(k)/colsum(exp k); colsum via all-ones B-fragment MFMA.
// Cross-wave combine: one-wave-at-a-time serial LDS reduce (atomics regressed).
__global__ __launch_bounds__(512, 2) void dd_fused(
    const unsigned short* __restrict__ qkv,
    unsigned short* __restrict__ ddT) {
  __shared__ __align__(16) char smem[123648];
  unsigned short* stg = (unsigned short*)smem;          // [8 waves][2][96*40]
  float* facc = (float*)smem;                           // alias: [96][100] fp32
  float* fsum = (float*)(smem + 122880);                // [96] colsum
  float* sinv = (float*)(smem + 123264);                // [96]

  const int bh = blockIdx.x, b = bh >> 3, h = bh & 7;
  const int t = threadIdx.x, w = t >> 6, l = t & 63;
  const int l15 = l & 15, lhi = l >> 4;

  unsigned short* myK = stg + w * 7680;
  unsigned short* myV = myK + 3840;
  const int n   = l >> 1;
  const int chh = l & 1;
  const size_t baseK = (size_t)b * N_TOK * GN + 768  + h * 96;
  const size_t baseV = baseK + 768;

  f32x4 acc[6][6], accS[6];
#pragma unroll
  for (int mf = 0; mf < 6; ++mf) {
    accS[mf] = (f32x4){0.f, 0.f, 0.f, 0.f};
#pragma unroll
    for (int nf = 0; nf < 6; ++nf) acc[mf][nf] = (f32x4){0.f, 0.f, 0.f, 0.f};
  }
  short8 ones;
#pragma unroll
  for (int j = 0; j < 8; ++j) ones[j] = (short)0x3F80;   // bf16 1.0

  for (int tt = 0; tt < 4; ++tt) {
    const int n0 = w * 128 + tt * 32;
    const size_t gk = baseK + (size_t)(n0 + n) * GN + chh * 48;
    const size_t gv = baseV + (size_t)(n0 + n) * GN + chh * 48;
#pragma unroll
    for (int i = 0; i < 6; ++i) {
      ushort8 k8 = *(const ushort8*)(qkv + gk + i * 8);
      ushort8 v8 = *(const ushort8*)(qkv + gv + i * 8);
      const int c0 = chh * 48 + i * 8;
#pragma unroll
      for (int j = 0; j < 8; ++j) {
        float e = __expf(bf2f(k8[j]));
        myK[(c0 + j) * 40 + n] = f2bf(e);
        myV[(c0 + j) * 40 + n] = v8[j];
      }
    }
    // same-wave DS ordering: compiler waits lgkmcnt before dependent reads
    short8 af[6], bf8[6];
#pragma unroll
    for (int mf = 0; mf < 6; ++mf)
      af[mf] = *(const short8*)((const char*)myK + (mf * 16 + l15) * 80 + lhi * 16);
#pragma unroll
    for (int nf = 0; nf < 6; ++nf)
      bf8[nf] = *(const short8*)((const char*)myV + (nf * 16 + l15) * 80 + lhi * 16);
#pragma unroll
    for (int mf = 0; mf < 6; ++mf) {
#pragma unroll
      for (int nf = 0; nf < 6; ++nf)
        acc[mf][nf] = __builtin_amdgcn_mfma_f32_16x16x32_bf16(af[mf], bf8[nf], acc[mf][nf], 0, 0, 0);
      accS[mf] = __builtin_amdgcn_mfma_f32_16x16x32_bf16(af[mf], ones, accS[mf], 0, 0, 0);
    }
  }

  __syncthreads();   // staging dead; facc aliases it
  for (int ww = 0; ww < 8; ++ww) {
    if (w == ww) {
#pragma unroll
      for (int mf = 0; mf < 6; ++mf) {
#pragma unroll
        for (int nf = 0; nf < 6; ++nf) {
          const int c = mf * 16 + lhi * 4, d = nf * 16 + l15;
#pragma unroll
          for (int r = 0; r < 4; ++r) {
            float* p = facc + (size_t)(c + r) * 100 + d;
            if (ww == 0) *p = acc[mf][nf][r]; else *p += acc[mf][nf][r];
          }
        }
        if (l15 == 0) {
          const int c = mf * 16 + lhi * 4;
#pragma unroll
          for (int r = 0; r < 4; ++r) {
            if (ww == 0) fsum[c + r] = accS[mf][r];
            else         fsum[c + r] += accS[mf][r];
          }
        }
      }
    }
    __syncthreads();
  }

  if (t < 96) sinv[t] = 1.0f / fsum[t];
  __syncthreads();

  unsigned short* dst = ddT + (size_t)bh * 9216;
#pragma unroll
  for (int e = 0; e < 18; ++e) {
    const int idx = t * 18 + e;
    const int d = idx / 96, c = idx % 96;
    dst[idx] = f2bf(facc[(size_t)c * 100 + d] * sinv[c]);
  }
}

// ---------------- out = SCALE*(q@dd) + q*dwconv3x3(v), persistent over tokens --
// grid (2 halves, 8 h, 32 b), 256 thr, 4 waves 2x2 of (32 rows x 48 cols).
// ddT + conv weights staged ONCE per block; loop over 8 token-tiles of 64.
__global__ __launch_bounds__(256) void factor_conv_p(
    const unsigned short* __restrict__ qkv,
    const unsigned short* __restrict__ ddT,    // [bh][96 d][96 c] bf16
    const float* __restrict__ wcr,             // [768][9]
    const float* __restrict__ bcr,             // [768]
    float* __restrict__ outb) {
  __shared__ __align__(16) unsigned short sQ[64 * 96];    // 12288 B
  __shared__ __align__(16) unsigned short sD[96 * 96];    // 18432 B
  __shared__ __align__(16) unsigned short sV[128 * 96];   // 24576 B (v halo: 4 img rows)
  __shared__ float sW[96 * 9];
  __shared__ float sBias[96];
  const int half = blockIdx.x, h = blockIdx.y, b = blockIdx.z;
  const int t = threadIdx.x, wv = t >> 6, l = t & 63;
  const int l15 = l & 15, lhi = l >> 4;
  const int bh = b * 8 + h;

  // ---- stage ddT + weights once
  const char* dg = (const char*)ddT + (size_t)bh * 18432;
#pragma unroll
  for (int it = 0; it < 4; ++it)
    gload_lds16(dg + (it * 256 + t) * 16, (char*)sD + it * 4096 + wv * 1024);
  if (wv < 2)
    gload_lds16(dg + (1024 + t) * 16, (char*)sD + 16384 + wv * 1024);
  for (int i = t; i < 960; i += 256) {
    if (i < 864) sW[i] = wcr[(size_t)(h * 96) * 9 + i];
    else         sBias[i - 864] = bcr[h * 96 + (i - 864)];
  }

  const char* qg0 = (const char*)qkv + ((size_t)b * N_TOK) * (GN * 2) + h * 192;
  const char* vg  = qg0 + 3072;
  const int wrow = (wv >> 1) * 32;
  const int wcol = (wv & 1) * 48;

  for (int it8 = 0; it8 < 8; ++it8) {
    const int nt = half * 8 + it8;
    const int n0 = nt * 64, y0 = nt * 2;

    // ---- stage q tile (64 rows x 96 cols)
#pragma unroll
    for (int it = 0; it < 3; ++it) {
      const int f = it * 256 + t;
      const int row = f / 12, ch = f % 12;
      gload_lds16(qg0 + (size_t)(n0 + row) * (GN * 2) + ch * 16,
                  (char*)sQ + it * 4096 + wv * 1024);
    }
    // ---- stage v halo (128 rows, clamped)
#pragma unroll
    for (int it = 0; it < 6; ++it) {
      const int f = it * 256 + t;
      const int row = f / 12, ch = f % 12;
      int tok = n0 - 32 + row;
      tok = tok < 0 ? 0 : (tok > 1023 ? 1023 : tok);
      gload_lds16(vg + (size_t)tok * (GN * 2) + ch * 16,
                  (char*)sV + it * 4096 + wv * 1024);
    }
    __syncthreads();   // drains vmcnt (incl. first-iter sD/weights)

    f32x4 acc[2][3];
#pragma unroll
    for (int m = 0; m < 2; ++m)
#pragma unroll
      for (int nn = 0; nn < 3; ++nn) acc[m][nn] = (f32x4){0.f, 0.f, 0.f, 0.f};

#pragma unroll
    for (int ks = 0; ks < 3; ++ks) {
      short8 af[2], bf8[3];
#pragma unroll
      for (int m = 0; m < 2; ++m)
        af[m] = *(const short8*)((const char*)sQ + (wrow + m*16 + l15) * 192 + ks * 64 + lhi * 16);
#pragma unroll
      for (int nn = 0; nn < 3; ++nn)
        bf8[nn] = *(const short8*)((const char*)sD + (wcol + nn*16 + l15) * 192 + ks * 64 + lhi * 16);
#pragma unroll
      for (int m = 0; m < 2; ++m)
#pragma unroll
        for (int nn = 0; nn < 3; ++nn)
          acc[m][nn] = __builtin_amdgcn_mfma_f32_16x16x32_bf16(af[m], bf8[nn], acc[m][nn], 0, 0, 0);
    }

    // epilogue: conv from sV, out = SCALE*acc + q*conv
#pragma unroll
    for (int nn = 0; nn < 3; ++nn) {
      const int dc = wcol + nn * 16 + l15;
      float w9[9];
#pragma unroll
      for (int k = 0; k < 9; ++k) w9[k] = sW[dc * 9 + k];
      const float bv = sBias[dc];
#pragma unroll
      for (int m = 0; m < 2; ++m) {
        const int rl0 = wrow + m * 16 + lhi * 4;     // 4 consecutive rows, same img y
        const int x = rl0 & 31, yl = rl0 >> 5;
        float cs[3][6];
#pragma unroll
        for (int dy = 0; dy < 3; ++dy) {
          const int gy = y0 + yl + dy - 1;
          const bool vy = (gy >= 0) && (gy < 32);
#pragma unroll
          for (int i = 0; i < 6; ++i) {
            const int xx = x - 1 + i;
            cs[dy][i] = (vy && xx >= 0 && xx < 32)
                ? bf2f(sV[((yl + dy) * 32 + xx) * 96 + dc]) : 0.f;
          }
        }
#pragma unroll
        for (int r = 0; r < 4; ++r) {
          float conv = bv;
#pragma unroll
          for (int dy = 0; dy < 3; ++dy)
#pragma unroll
            for (int dx = 0; dx < 3; ++dx)
              conv += w9[dy * 3 + dx] * cs[dy][r + dx];
          const int row = rl0 + r;
          const float qv = bf2f(sQ[row * 96 + dc]);
          outb[((size_t)(b * N_TOK + n0 + row)) * C_DIM + h * 96 + dc] =
              SCALE_F * acc[m][nn][r] + qv * conv;
        }
      }
    }
    __syncthreads();   // all sQ/sV readers done before next iter's stage
  }
}

extern "C" void kernel_launch(void* const* d_in, const int* in_sizes, int n_in,
                              void* d_out, int out_size, void* d_ws, size_t ws_size,
                              hipStream_t stream) {
  const float* x      = (const float*)d_in[0];
  const float* w_qkv  = (const float*)d_in[1];
  const float* w_crpe = (const float*)d_in[2];
  const float* b_crpe = (const float*)d_in[3];
  float* out = (float*)d_out;

  char* ws = (char*)d_ws;
  unsigned short* xb    = (unsigned short*)ws;                          // 48 MB
  unsigned short* wb    = (unsigned short*)(ws + 50331648);             // 3.4 MB
  unsigned short* qkv   = (unsigned short*)(ws + 50331648 + 3538944);   // 144 MB
  unsigned short* ddT   = (unsigned short*)(ws + 204865536);            // 4.7 MB bf16

  f32_to_bf16_all<<<dim3((NX4 + NW4 + 255) / 256), 256, 0, stream>>>(
      (const float4*)x, (ushort4*)xb, (const float4*)w_qkv, (ushort4*)wb);
  qkv_gemm_p<<<dim3(1152), 512, 0, stream>>>(xb, wb, qkv);
  dd_fused<<<dim3(B_SZ * HEADS), 512, 0, stream>>>(qkv, ddT);
  factor_conv_p<<<dim3(2, HEADS, B_SZ), 256, 0, stream>>>(qkv, ddT, w_crpe, b_crpe, out);
}

// Round 8
// 269.664 us; speedup vs baseline: 1.3489x; 1.1016x over previous
//
#include <hip/hip_runtime.h>
#include <stdint.h>

// Problem constants
#define B_SZ   32
#define N_TOK  1024
#define C_DIM  768
#define HEADS  8
#define CH_DIM 96
#define GM     32768          // B*N rows
#define GN     2304           // 3*C cols
#define GK     768            // K
#define SCALE_F 0.10206207261596577f   // 96^-0.5
#define WHICH_STRIDE 25165824u         // GM*768 elements per q/k/v tensor
#define BH_STRIDE    98304u            // 1024*96

typedef __attribute__((ext_vector_type(8))) short short8;
typedef __attribute__((ext_vector_type(8))) unsigned short ushort8;
typedef __attribute__((ext_vector_type(4))) float f32x4;

__device__ __forceinline__ float bf2f(unsigned short u) {
  union { unsigned int i; float f; } x; x.i = ((unsigned int)u) << 16; return x.f;
}
__device__ __forceinline__ unsigned short f2bf(float f) {
  union { float f; unsigned int i; } x; x.f = f;
  unsigned int r = x.i + 0x7fffu + ((x.i >> 16) & 1u);
  return (unsigned short)(r >> 16);
}

// async global->LDS, 16B/lane. LDS dest must be WAVE-UNIFORM; HW adds lane*16.
__device__ __forceinline__ void gload_lds16(const void* g, void* l) {
  __builtin_amdgcn_global_load_lds(
      (const __attribute__((address_space(1))) unsigned int*)g,
      (__attribute__((address_space(3))) unsigned int*)l, 16, 0, 0);
}

// ---------------- fp32 -> bf16 convert (both inputs, one launch) ---------------
#define NX4 (GM * GK / 4)
#define NW4 (GN * GK / 4)
__global__ void f32_to_bf16_all(const float4* __restrict__ x, ushort4* __restrict__ xb,
                                const float4* __restrict__ wq, ushort4* __restrict__ wbo) {
  int i = blockIdx.x * 256 + threadIdx.x;
  const float4* src; ushort4* dst; int j;
  if (i < NX4) { src = x; dst = xb; j = i; }
  else { j = i - NX4; if (j >= NW4) return; src = wq; dst = wbo; }
  float4 v = src[j];
  ushort4 o;
  o.x = f2bf(v.x); o.y = f2bf(v.y); o.z = f2bf(v.z); o.w = f2bf(v.w);
  dst[j] = o;
}

// ---------------- qkv GEMM, pipelined: 256x256 tile, BK=32, 4 LDS buffers ------
// 8 waves (2Mx4N), per-wave output 128x64 (acc[8][4]). Counted vmcnt(8).
// LDS swizzle: slot ^= (row>>1)&3 on BOTH stage-source and ds_read (verified:
// SQ_LDS_BANK_CONFLICT == 0). Epilogue: HEAD-MAJOR output [3][bh][n][96] with
// exp() fused for the k-third.
__global__ __launch_bounds__(512, 2) void qkv_gemm_p(
    const unsigned short* __restrict__ xb,   // [GM][768] bf16
    const unsigned short* __restrict__ wb,   // [GN][768] bf16 (B^T layout)
    unsigned short* __restrict__ qkv) {      // [3][bh][n][96] bf16
  __shared__ __align__(16) char lds[4][2][16384];   // [buf][A|B][256 rows x 64B]

  const int t = threadIdx.x, w = t >> 6, l = t & 63;
  const int l15 = l & 15, lhi = l >> 4;

  // XCD-aware bijective swizzle: nwg = 1152 = 8 * 144
  const int bid = blockIdx.x;
  const int swz = (bid & 7) * 144 + (bid >> 3);
  const int brow = (swz / 9) * 256;
  const int bcol = (swz % 9) * 256;
  const int wr = w >> 2, wc = w & 3;

  // staging source pre-swizzle: dst slot = l&3, local row = l>>2, (row>>1)&3 = (l>>3)&3
  const int s_colb = (((l & 3) ^ ((l >> 3) & 3)) << 4);
  const char* gA0 = (const char*)xb + (size_t)brow * 1536 + s_colb;
  const char* gB0 = (const char*)wb + (size_t)bcol * 1536 + s_colb;

  // frag read: row = base16 + l15 -> (row>>1)&3 = (l15>>1)&3
  const int rd_sw = (lhi * 16) ^ (((l15 >> 1) & 3) << 4);
  const int a_off = (wr * 128 + l15) * 64 + rd_sw;
  const int b_off = (wc * 64 + l15) * 64 + rd_sw;

  f32x4 acc[8][4];
#pragma unroll
  for (int m = 0; m < 8; ++m)
#pragma unroll
    for (int n = 0; n < 4; ++n) acc[m][n] = (f32x4){0.f, 0.f, 0.f, 0.f};

  auto STAGE = [&](int bi, int kt) {
#pragma unroll
    for (int rr = 0; rr < 2; ++rr) {
      const int rowA = (w + rr * 8) * 16 + (l >> 2);
      gload_lds16(gA0 + (size_t)rowA * 1536 + kt * 64,
                  &lds[bi][0][(w + rr * 8) * 1024]);
      gload_lds16(gB0 + (size_t)rowA * 1536 + kt * 64,
                  &lds[bi][1][(w + rr * 8) * 1024]);
    }
  };

  auto COMPUTE = [&](int bi) {
    short8 af[8], bf8[4];
#pragma unroll
    for (int n = 0; n < 4; ++n)
      bf8[n] = *(const short8*)(&lds[bi][1][b_off + n * 1024]);
#pragma unroll
    for (int m = 0; m < 8; ++m)
      af[m] = *(const short8*)(&lds[bi][0][a_off + m * 1024]);
    __builtin_amdgcn_s_setprio(1);
#pragma unroll
    for (int m = 0; m < 8; ++m)
#pragma unroll
      for (int n = 0; n < 4; ++n)
        acc[m][n] = __builtin_amdgcn_mfma_f32_16x16x32_bf16(af[m], bf8[n], acc[m][n], 0, 0, 0);
    __builtin_amdgcn_s_setprio(0);
  };

#define BARSYNC_VM(n) do {                                  \
    __builtin_amdgcn_sched_barrier(0);                      \
    asm volatile("s_waitcnt vmcnt(" #n ")" ::: "memory");   \
    __builtin_amdgcn_sched_barrier(0);                      \
    __builtin_amdgcn_s_barrier();                           \
    __builtin_amdgcn_sched_barrier(0);                      \
  } while (0)

  // prologue: 3 K-tiles in flight
  STAGE(0, 0); STAGE(1, 1); STAGE(2, 2);
  BARSYNC_VM(8);   // tile 0 landed (8 = tiles 1,2 outstanding)

  for (int kt = 0; kt < 21; ++kt) {
    STAGE((kt + 3) & 3, kt + 3);
    COMPUTE(kt & 3);
    BARSYNC_VM(8);
  }
  COMPUTE(1); BARSYNC_VM(4);
  COMPUTE(2); BARSYNC_VM(0);
  COMPUTE(3);

  // epilogue: C/D layout col=lane&15, row=(lane>>4)*4+reg.
  // Head-major dst: [which][b*8+h][tok][96]; exp fused for which==1 (k).
  const int bb = brow / 1024;          // whole block in one batch (256 | 1024)
#pragma unroll
  for (int m = 0; m < 8; ++m) {
    const int row0 = brow + wr * 128 + m * 16 + lhi * 4;
    const int tok0 = row0 & 1023;
#pragma unroll
    for (int n = 0; n < 4; ++n) {
      const int col   = bcol + wc * 64 + n * 16 + l15;
      const int which = col / 768;
      const int hh    = (col % 768) / 96;
      const int ch    = col % 96;
      unsigned short* dst = qkv + (size_t)which * WHICH_STRIDE
                          + ((size_t)(bb * 8 + hh)) * BH_STRIDE + ch;
#pragma unroll
      for (int r = 0; r < 4; ++r) {
        float v = acc[m][n][r];
        if (which == 1) v = __expf(v);
        dst[(size_t)(tok0 + r) * 96] = f2bf(v);
      }
    }
  }
#undef BARSYNC_VM
}

// ---------------- dd^T = (softmax(k)^T @ v)^T per (b,h) ------------------------
// k arrives PRE-EXP'd (fused in gemm epilogue) -> staging is pure u16 reorder.
// colsum via all-ones B-fragment MFMA; 2-region parallel reduce (waves 0-3/4-7).
__global__ __launch_bounds__(512, 2) void dd_fused(
    const unsigned short* __restrict__ qkv,
    unsigned short* __restrict__ ddT) {
  __shared__ __align__(16) char smem[124416];
  unsigned short* stg = (unsigned short*)smem;          // [8 waves][2][96*40]
  float* facc = (float*)smem;                           // alias: [2][96][100] fp32
  float* fsum = (float*)(smem + 122880);                // [2][96]
  float* sinv = (float*)(smem + 123648);                // [96]

  const int bh = blockIdx.x;
  const int t = threadIdx.x, w = t >> 6, l = t & 63;
  const int l15 = l & 15, lhi = l >> 4;

  unsigned short* myK = stg + w * 7680;
  unsigned short* myV = myK + 3840;
  const int n   = l >> 1;
  const int chh = l & 1;
  const unsigned short* kb = qkv + WHICH_STRIDE     + (size_t)bh * BH_STRIDE;
  const unsigned short* vb = qkv + 2 * WHICH_STRIDE + (size_t)bh * BH_STRIDE;

  f32x4 acc[6][6], accS[6];
#pragma unroll
  for (int mf = 0; mf < 6; ++mf) {
    accS[mf] = (f32x4){0.f, 0.f, 0.f, 0.f};
#pragma unroll
    for (int nf = 0; nf < 6; ++nf) acc[mf][nf] = (f32x4){0.f, 0.f, 0.f, 0.f};
  }
  short8 ones;
#pragma unroll
  for (int j = 0; j < 8; ++j) ones[j] = (short)0x3F80;   // bf16 1.0

  for (int tt = 0; tt < 4; ++tt) {
    const int n0 = w * 128 + tt * 32;
    const size_t g = (size_t)(n0 + n) * 96 + chh * 48;
#pragma unroll
    for (int i = 0; i < 6; ++i) {
      ushort8 k8 = *(const ushort8*)(kb + g + i * 8);
      ushort8 v8 = *(const ushort8*)(vb + g + i * 8);
      const int c0 = chh * 48 + i * 8;
#pragma unroll
      for (int j = 0; j < 8; ++j) {
        myK[(c0 + j) * 40 + n] = k8[j];
        myV[(c0 + j) * 40 + n] = v8[j];
      }
    }
    // same-wave DS ordering: compiler waits lgkmcnt before dependent reads
    short8 af[6], bf8[6];
#pragma unroll
    for (int mf = 0; mf < 6; ++mf)
      af[mf] = *(const short8*)((const char*)myK + (mf * 16 + l15) * 80 + lhi * 16);
#pragma unroll
    for (int nf = 0; nf < 6; ++nf)
      bf8[nf] = *(const short8*)((const char*)myV + (nf * 16 + l15) * 80 + lhi * 16);
#pragma unroll
    for (int mf = 0; mf < 6; ++mf) {
#pragma unroll
      for (int nf = 0; nf < 6; ++nf)
        acc[mf][nf] = __builtin_amdgcn_mfma_f32_16x16x32_bf16(af[mf], bf8[nf], acc[mf][nf], 0, 0, 0);
      accS[mf] = __builtin_amdgcn_mfma_f32_16x16x32_bf16(af[mf], ones, accS[mf], 0, 0, 0);
    }
  }

  __syncthreads();   // staging dead; facc aliases it
  float* fr  = facc + (w >> 2) * 9600;
  float* fsr = fsum + (w >> 2) * 96;
  for (int ww = 0; ww < 4; ++ww) {
    if ((w & 3) == ww) {
#pragma unroll
      for (int mf = 0; mf < 6; ++mf) {
#pragma unroll
        for (int nf = 0; nf < 6; ++nf) {
          const int c = mf * 16 + lhi * 4, d = nf * 16 + l15;
#pragma unroll
          for (int r = 0; r < 4; ++r) {
            float* p = fr + (size_t)(c + r) * 100 + d;
            if (ww == 0) *p = acc[mf][nf][r]; else *p += acc[mf][nf][r];
          }
        }
        if (l15 == 0) {
          const int c = mf * 16 + lhi * 4;
#pragma unroll
          for (int r = 0; r < 4; ++r) {
            if (ww == 0) fsr[c + r] = accS[mf][r];
            else         fsr[c + r] += accS[mf][r];
          }
        }
      }
    }
    __syncthreads();
  }
  // merge the two regions
  for (int i = t; i < 9600; i += 512) facc[i] += facc[9600 + i];
  if (t < 96) fsum[t] += fsum[96 + t];
  __syncthreads();
  if (t < 96) sinv[t] = 1.0f / fsum[t];
  __syncthreads();

  unsigned short* dst = ddT + (size_t)bh * 9216;
#pragma unroll
  for (int e = 0; e < 18; ++e) {
    const int idx = t * 18 + e;
    const int d = idx / 96, c = idx % 96;
    dst[idx] = f2bf(facc[(size_t)c * 100 + d] * sinv[c]);
  }
}

// ---------------- out = SCALE*(q@dd) + q*dwconv3x3(v), persistent over tokens --
// grid (2 halves, 8 h, 32 b), 256 thr, 4 waves 2x2 of (32 rows x 48 cols).
// q/v now head-major -> q tile is one contiguous 12 KB block.
__global__ __launch_bounds__(256) void factor_conv_p(
    const unsigned short* __restrict__ qkv,
    const unsigned short* __restrict__ ddT,    // [bh][96 d][96 c] bf16
    const float* __restrict__ wcr,             // [768][9]
    const float* __restrict__ bcr,             // [768]
    float* __restrict__ outb) {
  __shared__ __align__(16) unsigned short sQ[64 * 96];    // 12288 B
  __shared__ __align__(16) unsigned short sD[96 * 96];    // 18432 B
  __shared__ __align__(16) unsigned short sV[128 * 96];   // 24576 B (v halo: 4 img rows)
  __shared__ float sW[96 * 9];
  __shared__ float sBias[96];
  const int half = blockIdx.x, h = blockIdx.y, b = blockIdx.z;
  const int t = threadIdx.x, wv = t >> 6, l = t & 63;
  const int l15 = l & 15, lhi = l >> 4;
  const int bh = b * 8 + h;

  // ---- stage ddT + weights once
  const char* dg = (const char*)ddT + (size_t)bh * 18432;
#pragma unroll
  for (int it = 0; it < 4; ++it)
    gload_lds16(dg + (it * 256 + t) * 16, (char*)sD + it * 4096 + wv * 1024);
  if (wv < 2)
    gload_lds16(dg + (1024 + t) * 16, (char*)sD + 16384 + wv * 1024);
  for (int i = t; i < 960; i += 256) {
    if (i < 864) sW[i] = wcr[(size_t)(h * 96) * 9 + i];
    else         sBias[i - 864] = bcr[h * 96 + (i - 864)];
  }

  const char* qg = (const char*)(qkv + (size_t)bh * BH_STRIDE);
  const char* vg = (const char*)(qkv + 2 * WHICH_STRIDE + (size_t)bh * BH_STRIDE);
  const int wrow = (wv >> 1) * 32;
  const int wcol = (wv & 1) * 48;

  for (int it8 = 0; it8 < 8; ++it8) {
    const int nt = half * 8 + it8;
    const int n0 = nt * 64, y0 = nt * 2;

    // ---- stage q tile (contiguous 12288 B)
#pragma unroll
    for (int it = 0; it < 3; ++it)
      gload_lds16(qg + (size_t)n0 * 192 + (it * 256 + t) * 16,
                  (char*)sQ + it * 4096 + wv * 1024);
    // ---- stage v halo (128 rows, clamped)
#pragma unroll
    for (int it = 0; it < 6; ++it) {
      const int f = it * 256 + t;
      const int row = f / 12, ch = f % 12;
      int tok = n0 - 32 + row;
      tok = tok < 0 ? 0 : (tok > 1023 ? 1023 : tok);
      gload_lds16(vg + (size_t)tok * 192 + ch * 16,
                  (char*)sV + it * 4096 + wv * 1024);
    }
    __syncthreads();   // drains vmcnt (incl. first-iter sD/weights)

    f32x4 acc[2][3];
#pragma unroll
    for (int m = 0; m < 2; ++m)
#pragma unroll
      for (int nn = 0; nn < 3; ++nn) acc[m][nn] = (f32x4){0.f, 0.f, 0.f, 0.f};

#pragma unroll
    for (int ks = 0; ks < 3; ++ks) {
      short8 af[2], bf8[3];
#pragma unroll
      for (int m = 0; m < 2; ++m)
        af[m] = *(const short8*)((const char*)sQ + (wrow + m*16 + l15) * 192 + ks * 64 + lhi * 16);
#pragma unroll
      for (int nn = 0; nn < 3; ++nn)
        bf8[nn] = *(const short8*)((const char*)sD + (wcol + nn*16 + l15) * 192 + ks * 64 + lhi * 16);
#pragma unroll
      for (int m = 0; m < 2; ++m)
#pragma unroll
        for (int nn = 0; nn < 3; ++nn)
          acc[m][nn] = __builtin_amdgcn_mfma_f32_16x16x32_bf16(af[m], bf8[nn], acc[m][nn], 0, 0, 0);
    }

    // epilogue: conv from sV, out = SCALE*acc + q*conv
#pragma unroll
    for (int nn = 0; nn < 3; ++nn) {
      const int dc = wcol + nn * 16 + l15;
      float w9[9];
#pragma unroll
      for (int k = 0; k < 9; ++k) w9[k] = sW[dc * 9 + k];
      const float bv = sBias[dc];
#pragma unroll
      for (int m = 0; m < 2; ++m) {
        const int rl0 = wrow + m * 16 + lhi * 4;     // 4 consecutive rows, same img y
        const int x = rl0 & 31, yl = rl0 >> 5;
        float cs[3][6];
#pragma unroll
        for (int dy = 0; dy < 3; ++dy) {
          const int gy = y0 + yl + dy - 1;
          const bool vy = (gy >= 0) && (gy < 32);
#pragma unroll
          for (int i = 0; i < 6; ++i) {
            const int xx = x - 1 + i;
            cs[dy][i] = (vy && xx >= 0 && xx < 32)
                ? bf2f(sV[((yl + dy) * 32 + xx) * 96 + dc]) : 0.f;
          }
        }
#pragma unroll
        for (int r = 0; r < 4; ++r) {
          float conv = bv;
#pragma unroll
          for (int dy = 0; dy < 3; ++dy)
#pragma unroll
            for (int dx = 0; dx < 3; ++dx)
              conv += w9[dy * 3 + dx] * cs[dy][r + dx];
          const int row = rl0 + r;
          const float qv = bf2f(sQ[row * 96 + dc]);
          outb[((size_t)(b * N_TOK + n0 + row)) * C_DIM + h * 96 + dc] =
              SCALE_F * acc[m][nn][r] + qv * conv;
        }
      }
    }
    __syncthreads();   // all sQ/sV readers done before next iter's stage
  }
}

extern "C" void kernel_launch(void* const* d_in, const int* in_sizes, int n_in,
                              void* d_out, int out_size, void* d_ws, size_t ws_size,
                              hipStream_t stream) {
  const float* x      = (const float*)d_in[0];
  const float* w_qkv  = (const float*)d_in[1];
  const float* w_crpe = (const float*)d_in[2];
  const float* b_crpe = (const float*)d_in[3];
  float* out = (float*)d_out;

  char* ws = (char*)d_ws;
  unsigned short* xb    = (unsigned short*)ws;                          // 48 MB
  unsigned short* wb    = (unsigned short*)(ws + 50331648);             // 3.4 MB
  unsigned short* qkv   = (unsigned short*)(ws + 50331648 + 3538944);   // 144 MB, [3][bh][n][96]
  unsigned short* ddT   = (unsigned short*)(ws + 204865536);            // 4.7 MB bf16

  f32_to_bf16_all<<<dim3((NX4 + NW4 + 255) / 256), 256, 0, stream>>>(
      (const float4*)x, (ushort4*)xb, (const float4*)w_qkv, (ushort4*)wb);
  qkv_gemm_p<<<dim3(1152), 512, 0, stream>>>(xb, wb, qkv);
  dd_fused<<<dim3(B_SZ * HEADS), 512, 0, stream>>>(qkv, ddT);
  factor_conv_p<<<dim3(2, HEADS, B_SZ), 256, 0, stream>>>(qkv, ddT, w_crpe, b_crpe, out);
}

// Round 10
// 224.692 us; speedup vs baseline: 1.6188x; 1.2001x over previous
//
#include <hip/hip_runtime.h>
#include <stdint.h>

// Problem constants
#define B_SZ   32
#define N_TOK  1024
#define C_DIM  768
#define HEADS  8
#define CH_DIM 96
#define GM     32768          // B*N rows
#define GN     2304           // 3*C cols
#define GK     768            // K
#define SCALE_F 0.10206207261596577f   // 96^-0.5
#define WHICH_STRIDE 25165824u         // GM*768 elements per q/k/v tensor
#define BH_STRIDE    98304u            // 1024*96

typedef __attribute__((ext_vector_type(8))) short short8;
typedef __attribute__((ext_vector_type(8))) unsigned short ushort8;
typedef __attribute__((ext_vector_type(4))) float f32x4;
typedef __attribute__((ext_vector_type(4))) int int4v;

__device__ __forceinline__ float bf2f(unsigned short u) {
  union { unsigned int i; float f; } x; x.i = ((unsigned int)u) << 16; return x.f;
}
__device__ __forceinline__ unsigned short f2bf(float f) {
  union { float f; unsigned int i; } x; x.f = f;
  unsigned int r = x.i + 0x7fffu + ((x.i >> 16) & 1u);
  return (unsigned short)(r >> 16);
}

// async global->LDS, 16B/lane. LDS dest must be WAVE-UNIFORM; HW adds lane*16.
__device__ __forceinline__ void gload_lds16(const void* g, void* l) {
  __builtin_amdgcn_global_load_lds(
      (const __attribute__((address_space(1))) unsigned int*)g,
      (__attribute__((address_space(3))) unsigned int*)l, 16, 0, 0);
}

// ---------------- fp32 -> int8 per-row dynamic quantization --------------------
// One wave per 768-elem row: shuffle max-reduce, scale = 127/rowmax (no clipping
// ever), store inv scale for epilogue dequant. Rows < GM are x; rest are w_qkv.
__global__ __launch_bounds__(256) void quant_rows(
    const float* __restrict__ x, const float* __restrict__ wq,
    signed char* __restrict__ xq, signed char* __restrict__ wqo,
    float* __restrict__ inv_x, float* __restrict__ inv_w) {
  const int row = blockIdx.x * 4 + (threadIdx.x >> 6);
  const int l = threadIdx.x & 63;
  const float* src; signed char* dst; float* inv; int r;
  if (row < GM) { src = x;  dst = xq;  inv = inv_x; r = row; }
  else { r = row - GM; if (r >= GN) return; src = wq; dst = wqo; inv = inv_w; }

  const float4* s4 = (const float4*)(src + (size_t)r * 768);
  float4 v0 = s4[l], v1 = s4[l + 64], v2 = s4[l + 128];
  float m = fmaxf(fmaxf(fmaxf(fabsf(v0.x), fabsf(v0.y)), fmaxf(fabsf(v0.z), fabsf(v0.w))),
                  fmaxf(fmaxf(fabsf(v1.x), fabsf(v1.y)), fmaxf(fabsf(v1.z), fabsf(v1.w))));
  m = fmaxf(m, fmaxf(fmaxf(fabsf(v2.x), fabsf(v2.y)), fmaxf(fabsf(v2.z), fabsf(v2.w))));
#pragma unroll
  for (int off = 32; off; off >>= 1) m = fmaxf(m, __shfl_xor(m, off));
  const float sc = 127.0f / m;
  if (l == 0) inv[r] = m * (1.0f / 127.0f);

  char4* d4 = (char4*)(dst + (size_t)r * 768);
  char4 o;
  o.x = (signed char)(int)rintf(v0.x * sc); o.y = (signed char)(int)rintf(v0.y * sc);
  o.z = (signed char)(int)rintf(v0.z * sc); o.w = (signed char)(int)rintf(v0.w * sc);
  d4[l] = o;
  o.x = (signed char)(int)rintf(v1.x * sc); o.y = (signed char)(int)rintf(v1.y * sc);
  o.z = (signed char)(int)rintf(v1.z * sc); o.w = (signed char)(int)rintf(v1.w * sc);
  d4[l + 64] = o;
  o.x = (signed char)(int)rintf(v2.x * sc); o.y = (signed char)(int)rintf(v2.y * sc);
  o.z = (signed char)(int)rintf(v2.z * sc); o.w = (signed char)(int)rintf(v2.w * sc);
  d4[l + 128] = o;
}

// ---------------- qkv GEMM, int8 MFMA, pipelined: 256x256 tile, BK=64 ----------
// 8 waves (2Mx4N), per-wave output 128x64 (acc[8][4]). mfma_i32_16x16x64_i8:
// K=64 i8 = 64 B/row -> IDENTICAL LDS geometry/swizzle as the bf16 BK=32 version
// (verified SQ_LDS_BANK_CONFLICT == 0). 12 K-tiles, 4 buffers, counted vmcnt(8).
// Epilogue: per-row dequant acc*inv_x[row]*inv_w[col], head-major, exp for k.
__global__ __launch_bounds__(512, 2) void qkv_gemm_i8(
    const signed char* __restrict__ xb,   // [GM][768] i8
    const signed char* __restrict__ wb,   // [GN][768] i8 (B^T layout)
    const float* __restrict__ inv_x,      // [GM]
    const float* __restrict__ inv_w,      // [GN]
    unsigned short* __restrict__ qkv) {   // [3][bh][n][96] bf16
  __shared__ __align__(16) char lds[4][2][16384];   // [buf][A|B][256 rows x 64B]

  const int t = threadIdx.x, w = t >> 6, l = t & 63;
  const int l15 = l & 15, lhi = l >> 4;

  // XCD-aware bijective swizzle: nwg = 1152 = 8 * 144
  const int bid = blockIdx.x;
  const int swz = (bid & 7) * 144 + (bid >> 3);
  const int brow = (swz / 9) * 256;
  const int bcol = (swz % 9) * 256;
  const int wr = w >> 2, wc = w & 3;

  // staging source pre-swizzle: dst slot = l&3, local row = l>>2, (row>>1)&3 = (l>>3)&3
  const int s_colb = (((l & 3) ^ ((l >> 3) & 3)) << 4);
  const char* gA0 = (const char*)xb + (size_t)brow * 768 + s_colb;
  const char* gB0 = (const char*)wb + (size_t)bcol * 768 + s_colb;

  // frag read: row = base16 + l15 -> (row>>1)&3 = (l15>>1)&3
  const int rd_sw = (lhi * 16) ^ (((l15 >> 1) & 3) << 4);
  const int a_off = (wr * 128 + l15) * 64 + rd_sw;
  const int b_off = (wc * 64 + l15) * 64 + rd_sw;

  int4v acc[8][4];
#pragma unroll
  for (int m = 0; m < 8; ++m)
#pragma unroll
    for (int n = 0; n < 4; ++n) acc[m][n] = (int4v){0, 0, 0, 0};

  auto STAGE = [&](int bi, int kt) {
#pragma unroll
    for (int rr = 0; rr < 2; ++rr) {
      const int rowA = (w + rr * 8) * 16 + (l >> 2);
      gload_lds16(gA0 + (size_t)rowA * 768 + kt * 64,
                  &lds[bi][0][(w + rr * 8) * 1024]);
      gload_lds16(gB0 + (size_t)rowA * 768 + kt * 64,
                  &lds[bi][1][(w + rr * 8) * 1024]);
    }
  };

  auto COMPUTE = [&](int bi) {
    int4v af[8], bf8[4];
#pragma unroll
    for (int n = 0; n < 4; ++n)
      bf8[n] = *(const int4v*)(&lds[bi][1][b_off + n * 1024]);
#pragma unroll
    for (int m = 0; m < 8; ++m)
      af[m] = *(const int4v*)(&lds[bi][0][a_off + m * 1024]);
    __builtin_amdgcn_s_setprio(1);
#pragma unroll
    for (int m = 0; m < 8; ++m)
#pragma unroll
      for (int n = 0; n < 4; ++n)
        acc[m][n] = __builtin_amdgcn_mfma_i32_16x16x64_i8(af[m], bf8[n], acc[m][n], 0, 0, 0);
    __builtin_amdgcn_s_setprio(0);
  };

#define BARSYNC_VM(n) do {                                  \
    __builtin_amdgcn_sched_barrier(0);                      \
    asm volatile("s_waitcnt vmcnt(" #n ")" ::: "memory");   \
    __builtin_amdgcn_sched_barrier(0);                      \
    __builtin_amdgcn_s_barrier();                           \
    __builtin_amdgcn_sched_barrier(0);                      \
  } while (0)

  // prologue: 3 K-tiles in flight (12 loads)
  STAGE(0, 0); STAGE(1, 1); STAGE(2, 2);
  BARSYNC_VM(8);   // tile 0 landed

  for (int kt = 0; kt < 9; ++kt) {
    STAGE((kt + 3) & 3, kt + 3);   // kt+3 <= 11
    COMPUTE(kt & 3);
    BARSYNC_VM(8);
  }
  COMPUTE(1); BARSYNC_VM(4);       // kt=9
  COMPUTE(2); BARSYNC_VM(0);       // kt=10
  COMPUTE(3);                      // kt=11

  // epilogue: C/D layout col=lane&15, row=(lane>>4)*4+reg (dtype-independent).
  // Head-major dst: [which][b*8+h][tok][96]; dequant + exp fused for which==1.
  const int bb = brow / 1024;
#pragma unroll
  for (int m = 0; m < 8; ++m) {
    const int row0 = brow + wr * 128 + m * 16 + lhi * 4;
    const int tok0 = row0 & 1023;
    float ix[4];
#pragma unroll
    for (int r = 0; r < 4; ++r) ix[r] = inv_x[row0 + r];
#pragma unroll
    for (int n = 0; n < 4; ++n) {
      const int col   = bcol + wc * 64 + n * 16 + l15;
      const float dq0 = inv_w[col];
      const int which = col / 768;
      const int hh    = (col % 768) / 96;
      const int ch    = col % 96;
      unsigned short* dst = qkv + (size_t)which * WHICH_STRIDE
                          + ((size_t)(bb * 8 + hh)) * BH_STRIDE + ch;
#pragma unroll
      for (int r = 0; r < 4; ++r) {
        float v = (float)acc[m][n][r] * dq0 * ix[r];
        if (which == 1) v = __expf(v);
        dst[(size_t)(tok0 + r) * 96] = f2bf(v);
      }
    }
  }
#undef BARSYNC_VM
}

// ---------------- dd^T = (softmax(k)^T @ v)^T per (b,h) ------------------------
// k arrives PRE-EXP'd (fused in gemm epilogue) -> staging is pure u16 reorder.
// colsum via all-ones B-fragment MFMA; 2-region parallel reduce (waves 0-3/4-7).
__global__ __launch_bounds__(512, 2) void dd_fused(
    const unsigned short* __restrict__ qkv,
    unsigned short* __restrict__ ddT) {
  __shared__ __align__(16) char smem[124416];
  unsigned short* stg = (unsigned short*)smem;          // [8 waves][2][96*40]
  float* facc = (float*)smem;                           // alias: [2][96][100] fp32
  float* fsum = (float*)(smem + 122880);                // [2][96]
  float* sinv = (float*)(smem + 123648);                // [96]

  const int bh = blockIdx.x;
  const int t = threadIdx.x, w = t >> 6, l = t & 63;
  const int l15 = l & 15, lhi = l >> 4;

  unsigned short* myK = stg + w * 7680;
  unsigned short* myV = myK + 3840;
  const int n   = l >> 1;
  const int chh = l & 1;
  const unsigned short* kb = qkv + WHICH_STRIDE     + (size_t)bh * BH_STRIDE;
  const unsigned short* vb = qkv + 2 * WHICH_STRIDE + (size_t)bh * BH_STRIDE;

  f32x4 acc[6][6], accS[6];
#pragma unroll
  for (int mf = 0; mf < 6; ++mf) {
    accS[mf] = (f32x4){0.f, 0.f, 0.f, 0.f};
#pragma unroll
    for (int nf = 0; nf < 6; ++nf) acc[mf][nf] = (f32x4){0.f, 0.f, 0.f, 0.f};
  }
  short8 ones;
#pragma unroll
  for (int j = 0; j < 8; ++j) ones[j] = (short)0x3F80;   // bf16 1.0

  for (int tt = 0; tt < 4; ++tt) {
    const int n0 = w * 128 + tt * 32;
    const size_t g = (size_t)(n0 + n) * 96 + chh * 48;
#pragma unroll
    for (int i = 0; i < 6; ++i) {
      ushort8 k8 = *(const ushort8*)(kb + g + i * 8);
      ushort8 v8 = *(const ushort8*)(vb + g + i * 8);
      const int c0 = chh * 48 + i * 8;
#pragma unroll
      for (int j = 0; j < 8; ++j) {
        myK[(c0 + j) * 40 + n] = k8[j];
        myV[(c0 + j) * 40 + n] = v8[j];
      }
    }
    // same-wave DS ordering: compiler waits lgkmcnt before dependent reads
    short8 af[6], bf8[6];
#pragma unroll
    for (int mf = 0; mf < 6; ++mf)
      af[mf] = *(const short8*)((const char*)myK + (mf * 16 + l15) * 80 + lhi * 16);
#pragma unroll
    for (int nf = 0; nf < 6; ++nf)
      bf8[nf] = *(const short8*)((const char*)myV + (nf * 16 + l15) * 80 + lhi * 16);
#pragma unroll
    for (int mf = 0; mf < 6; ++mf) {
#pragma unroll
      for (int nf = 0; nf < 6; ++nf)
        acc[mf][nf] = __builtin_amdgcn_mfma_f32_16x16x32_bf16(af[mf], bf8[nf], acc[mf][nf], 0, 0, 0);
      accS[mf] = __builtin_amdgcn_mfma_f32_16x16x32_bf16(af[mf], ones, accS[mf], 0, 0, 0);
    }
  }

  __syncthreads();   // staging dead; facc aliases it
  float* fr  = facc + (w >> 2) * 9600;
  float* fsr = fsum + (w >> 2) * 96;
  for (int ww = 0; ww < 4; ++ww) {
    if ((w & 3) == ww) {
#pragma unroll
      for (int mf = 0; mf < 6; ++mf) {
#pragma unroll
        for (int nf = 0; nf < 6; ++nf) {
          const int c = mf * 16 + lhi * 4, d = nf * 16 + l15;
#pragma unroll
          for (int r = 0; r < 4; ++r) {
            float* p = fr + (size_t)(c + r) * 100 + d;
            if (ww == 0) *p = acc[mf][nf][r]; else *p += acc[mf][nf][r];
          }
        }
        if (l15 == 0) {
          const int c = mf * 16 + lhi * 4;
#pragma unroll
          for (int r = 0; r < 4; ++r) {
            if (ww == 0) fsr[c + r] = accS[mf][r];
            else         fsr[c + r] += accS[mf][r];
          }
        }
      }
    }
    __syncthreads();
  }
  // merge the two regions
  for (int i = t; i < 9600; i += 512) facc[i] += facc[9600 + i];
  if (t < 96) fsum[t] += fsum[96 + t];
  __syncthreads();
  if (t < 96) sinv[t] = 1.0f / fsum[t];
  __syncthreads();

  unsigned short* dst = ddT + (size_t)bh * 9216;
#pragma unroll
  for (int e = 0; e < 18; ++e) {
    const int idx = t * 18 + e;
    const int d = idx / 96, c = idx % 96;
    dst[idx] = f2bf(facc[(size_t)c * 100 + d] * sinv[c]);
  }
}

// ---------------- out = SCALE*(q@dd) + q*dwconv3x3(v), persistent over tokens --
// grid (2 halves, 8 h, 32 b), 256 thr, 4 waves 2x2 of (32 rows x 48 cols).
__global__ __launch_bounds__(256) void factor_conv_p(
    const unsigned short* __restrict__ qkv,
    const unsigned short* __restrict__ ddT,    // [bh][96 d][96 c] bf16
    const float* __restrict__ wcr,             // [768][9]
    const float* __restrict__ bcr,             // [768]
    float* __restrict__ outb) {
  __shared__ __align__(16) unsigned short sQ[64 * 96];    // 12288 B
  __shared__ __align__(16) unsigned short sD[96 * 96];    // 18432 B
  __shared__ __align__(16) unsigned short sV[128 * 96];   // 24576 B (v halo: 4 img rows)
  __shared__ float sW[96 * 9];
  __shared__ float sBias[96];
  const int half = blockIdx.x, h = blockIdx.y, b = blockIdx.z;
  const int t = threadIdx.x, wv = t >> 6, l = t & 63;
  const int l15 = l & 15, lhi = l >> 4;
  const int bh = b * 8 + h;

  // ---- stage ddT + weights once
  const char* dg = (const char*)ddT + (size_t)bh * 18432;
#pragma unroll
  for (int it = 0; it < 4; ++it)
    gload_lds16(dg + (it * 256 + t) * 16, (char*)sD + it * 4096 + wv * 1024);
  if (wv < 2)
    gload_lds16(dg + (1024 + t) * 16, (char*)sD + 16384 + wv * 1024);
  for (int i = t; i < 960; i += 256) {
    if (i < 864) sW[i] = wcr[(size_t)(h * 96) * 9 + i];
    else         sBias[i - 864] = bcr[h * 96 + (i - 864)];
  }

  const char* qg = (const char*)(qkv + (size_t)bh * BH_STRIDE);
  const char* vg = (const char*)(qkv + 2 * WHICH_STRIDE + (size_t)bh * BH_STRIDE);
  const int wrow = (wv >> 1) * 32;
  const int wcol = (wv & 1) * 48;

  for (int it8 = 0; it8 < 8; ++it8) {
    const int nt = half * 8 + it8;
    const int n0 = nt * 64, y0 = nt * 2;

    // ---- stage q tile (contiguous 12288 B)
#pragma unroll
    for (int it = 0; it < 3; ++it)
      gload_lds16(qg + (size_t)n0 * 192 + (it * 256 + t) * 16,
                  (char*)sQ + it * 4096 + wv * 1024);
    // ---- stage v halo (128 rows, clamped)
#pragma unroll
    for (int it = 0; it < 6; ++it) {
      const int f = it * 256 + t;
      const int row = f / 12, ch = f % 12;
      int tok = n0 - 32 + row;
      tok = tok < 0 ? 0 : (tok > 1023 ? 1023 : tok);
      gload_lds16(vg + (size_t)tok * 192 + ch * 16,
                  (char*)sV + it * 4096 + wv * 1024);
    }
    __syncthreads();   // drains vmcnt (incl. first-iter sD/weights)

    f32x4 acc[2][3];
#pragma unroll
    for (int m = 0; m < 2; ++m)
#pragma unroll
      for (int nn = 0; nn < 3; ++nn) acc[m][nn] = (f32x4){0.f, 0.f, 0.f, 0.f};

#pragma unroll
    for (int ks = 0; ks < 3; ++ks) {
      short8 af[2], bf8[3];
#pragma unroll
      for (int m = 0; m < 2; ++m)
        af[m] = *(const short8*)((const char*)sQ + (wrow + m*16 + l15) * 192 + ks * 64 + lhi * 16);
#pragma unroll
      for (int nn = 0; nn < 3; ++nn)
        bf8[nn] = *(const short8*)((const char*)sD + (wcol + nn*16 + l15) * 192 + ks * 64 + lhi * 16);
#pragma unroll
      for (int m = 0; m < 2; ++m)
#pragma unroll
        for (int nn = 0; nn < 3; ++nn)
          acc[m][nn] = __builtin_amdgcn_mfma_f32_16x16x32_bf16(af[m], bf8[nn], acc[m][nn], 0, 0, 0);
    }

    // epilogue: conv from sV, out = SCALE*acc + q*conv
#pragma unroll
    for (int nn = 0; nn < 3; ++nn) {
      const int dc = wcol + nn * 16 + l15;
      float w9[9];
#pragma unroll
      for (int k = 0; k < 9; ++k) w9[k] = sW[dc * 9 + k];
      const float bv = sBias[dc];
#pragma unroll
      for (int m = 0; m < 2; ++m) {
        const int rl0 = wrow + m * 16 + lhi * 4;     // 4 consecutive rows, same img y
        const int x = rl0 & 31, yl = rl0 >> 5;
        float cs[3][6];
#pragma unroll
        for (int dy = 0; dy < 3; ++dy) {
          const int gy = y0 + yl + dy - 1;
          const bool vy = (gy >= 0) && (gy < 32);
#pragma unroll
          for (int i = 0; i < 6; ++i) {
            const int xx = x - 1 + i;
            cs[dy][i] = (vy && xx >= 0 && xx < 32)
                ? bf2f(sV[((yl + dy) * 32 + xx) * 96 + dc]) : 0.f;
          }
        }
#pragma unroll
        for (int r = 0; r < 4; ++r) {
          float conv = bv;
#pragma unroll
          for (int dy = 0; dy < 3; ++dy)
#pragma unroll
            for (int dx = 0; dx < 3; ++dx)
              conv += w9[dy * 3 + dx] * cs[dy][r + dx];
          const int row = rl0 + r;
          const float qv = bf2f(sQ[row * 96 + dc]);
          outb[((size_t)(b * N_TOK + n0 + row)) * C_DIM + h * 96 + dc] =
              SCALE_F * acc[m][nn][r] + qv * conv;
        }
      }
    }
    __syncthreads();   // all sQ/sV readers done before next iter's stage
  }
}

extern "C" void kernel_launch(void* const* d_in, const int* in_sizes, int n_in,
                              void* d_out, int out_size, void* d_ws, size_t ws_size,
                              hipStream_t stream) {
  const float* x      = (const float*)d_in[0];
  const float* w_qkv  = (const float*)d_in[1];
  const float* w_crpe = (const float*)d_in[2];
  const float* b_crpe = (const float*)d_in[3];
  float* out = (float*)d_out;

  char* ws = (char*)d_ws;
  signed char*    xq    = (signed char*)ws;                             // 24 MB i8
  signed char*    wq    = (signed char*)(ws + 25165824);                // 1.7 MB i8
  float*          inv_x = (float*)(ws + 27000832);                      // 128 KB
  float*          inv_w = (float*)(ws + 27131904);                      // 9 KB
  unsigned short* qkv   = (unsigned short*)(ws + 53870592);             // 144 MB, [3][bh][n][96]
  unsigned short* ddT   = (unsigned short*)(ws + 204865536);            // 4.7 MB bf16

  quant_rows<<<dim3((GM + GN + 3) / 4), 256, 0, stream>>>(
      x, w_qkv, xq, wq, inv_x, inv_w);
  qkv_gemm_i8<<<dim3(1152), 512, 0, stream>>>(xq, wq, inv_x, inv_w, qkv);
  dd_fused<<<dim3(B_SZ * HEADS), 512, 0, stream>>>(qkv, ddT);
  factor_conv_p<<<dim3(2, HEADS, B_SZ), 256, 0, stream>>>(qkv, ddT, w_crpe, b_crpe, out);
}

// Round 11
// 216.129 us; speedup vs baseline: 1.6830x; 1.0396x over previous
//
#include <hip/hip_runtime.h>
#include <stdint.h>

// Problem constants
#define B_SZ   32
#define N_TOK  1024
#define C_DIM  768
#define HEADS  8
#define CH_DIM 96
#define GM     32768          // B*N rows
#define GN     2304           // 3*C cols
#define GK     768            // K
#define SCALE_F 0.10206207261596577f   // 96^-0.5
#define WHICH_STRIDE 25165824u         // GM*768 elements per q/k/v tensor
#define BH_STRIDE    98304u            // 1024*96

typedef __attribute__((ext_vector_type(8))) short short8;
typedef __attribute__((ext_vector_type(8))) unsigned short ushort8;
typedef __attribute__((ext_vector_type(4))) float f32x4;
typedef __attribute__((ext_vector_type(4))) int int4v;

__device__ __forceinline__ float bf2f(unsigned short u) {
  union { unsigned int i; float f; } x; x.i = ((unsigned int)u) << 16; return x.f;
}
__device__ __forceinline__ unsigned short f2bf(float f) {
  union { float f; unsigned int i; } x; x.f = f;
  unsigned int r = x.i + 0x7fffu + ((x.i >> 16) & 1u);
  return (unsigned short)(r >> 16);
}

// async global->LDS, 16B/lane. LDS dest must be WAVE-UNIFORM; HW adds lane*16.
__device__ __forceinline__ void gload_lds16(const void* g, void* l) {
  __builtin_amdgcn_global_load_lds(
      (const __attribute__((address_space(1))) unsigned int*)g,
      (__attribute__((address_space(3))) unsigned int*)l, 16, 0, 0);
}

// ---------------- fp32 -> int8 per-row dynamic quantization --------------------
// One wave per 768-elem row: shuffle max-reduce, scale = 127/rowmax (no clipping
// ever), store inv scale for epilogue dequant. Rows < GM are x; rest are w_qkv.
__global__ __launch_bounds__(256) void quant_rows(
    const float* __restrict__ x, const float* __restrict__ wq,
    signed char* __restrict__ xq, signed char* __restrict__ wqo,
    float* __restrict__ inv_x, float* __restrict__ inv_w) {
  const int row = blockIdx.x * 4 + (threadIdx.x >> 6);
  const int l = threadIdx.x & 63;
  const float* src; signed char* dst; float* inv; int r;
  if (row < GM) { src = x;  dst = xq;  inv = inv_x; r = row; }
  else { r = row - GM; if (r >= GN) return; src = wq; dst = wqo; inv = inv_w; }

  const float4* s4 = (const float4*)(src + (size_t)r * 768);
  float4 v0 = s4[l], v1 = s4[l + 64], v2 = s4[l + 128];
  float m = fmaxf(fmaxf(fmaxf(fabsf(v0.x), fabsf(v0.y)), fmaxf(fabsf(v0.z), fabsf(v0.w))),
                  fmaxf(fmaxf(fabsf(v1.x), fabsf(v1.y)), fmaxf(fabsf(v1.z), fabsf(v1.w))));
  m = fmaxf(m, fmaxf(fmaxf(fabsf(v2.x), fabsf(v2.y)), fmaxf(fabsf(v2.z), fabsf(v2.w))));
#pragma unroll
  for (int off = 32; off; off >>= 1) m = fmaxf(m, __shfl_xor(m, off));
  const float sc = 127.0f / m;
  if (l == 0) inv[r] = m * (1.0f / 127.0f);

  char4* d4 = (char4*)(dst + (size_t)r * 768);
  char4 o;
  o.x = (signed char)(int)rintf(v0.x * sc); o.y = (signed char)(int)rintf(v0.y * sc);
  o.z = (signed char)(int)rintf(v0.z * sc); o.w = (signed char)(int)rintf(v0.w * sc);
  d4[l] = o;
  o.x = (signed char)(int)rintf(v1.x * sc); o.y = (signed char)(int)rintf(v1.y * sc);
  o.z = (signed char)(int)rintf(v1.z * sc); o.w = (signed char)(int)rintf(v1.w * sc);
  d4[l + 64] = o;
  o.x = (signed char)(int)rintf(v2.x * sc); o.y = (signed char)(int)rintf(v2.y * sc);
  o.z = (signed char)(int)rintf(v2.z * sc); o.w = (signed char)(int)rintf(v2.w * sc);
  d4[l + 128] = o;
}

// ---------------- qkv GEMM, int8 MFMA: 128x256 tile, 2 LDS buffers, 2 blk/CU ---
// 8 waves (2M x 4N), per-wave output 64x64 (acc[4][4] = 64 VGPR). 48 KB LDS ->
// 2 blocks/CU: barrier/vmcnt drains in one block overlap compute in the other.
// Double-buffer, counted vmcnt(3) (3 loads/thread/STAGE, FIFO retire).
// Swizzle slot ^= (row>>1)&3 both-sides (verified conflict-free).
__global__ __launch_bounds__(512, 4) void qkv_gemm_i8(
    const signed char* __restrict__ xb,   // [GM][768] i8
    const signed char* __restrict__ wb,   // [GN][768] i8 (B^T layout)
    const float* __restrict__ inv_x,      // [GM]
    const float* __restrict__ inv_w,      // [GN]
    unsigned short* __restrict__ qkv) {   // [3][bh][n][96] bf16
  __shared__ __align__(16) char lds[2][24576];   // [buf][A 8KB | B 16KB]

  const int t = threadIdx.x, w = t >> 6, l = t & 63;
  const int l15 = l & 15, lhi = l >> 4;

  // XCD-aware bijective swizzle: nwg = 2304 = 8 * 288
  const int bid = blockIdx.x;
  const int swz = (bid & 7) * 288 + (bid >> 3);
  const int brow = (swz / 9) * 128;
  const int bcol = (swz % 9) * 256;
  const int wr = w >> 2, wc = w & 3;

  // staging source pre-swizzle: dst slot = l&3, local row = l>>2, (row>>1)&3 = (l>>3)&3
  const int s_colb = (((l & 3) ^ ((l >> 3) & 3)) << 4);
  const char* gA0 = (const char*)xb + (size_t)brow * 768 + s_colb;
  const char* gB0 = (const char*)wb + (size_t)bcol * 768 + s_colb;

  // frag read: row = base16 + l15 -> (row>>1)&3 = (l15>>1)&3
  const int rd_sw = (lhi * 16) ^ (((l15 >> 1) & 3) << 4);
  const int a_off = (wr * 64 + l15) * 64 + rd_sw;          // within A (8 KB)
  const int b_off = 8192 + (wc * 64 + l15) * 64 + rd_sw;   // within B (16 KB)

  int4v acc[4][4];
#pragma unroll
  for (int m = 0; m < 4; ++m)
#pragma unroll
    for (int n = 0; n < 4; ++n) acc[m][n] = (int4v){0, 0, 0, 0};

  auto STAGE = [&](int bi, int kt) {
    const int rowL = w * 16 + (l >> 2);      // 0..127
    gload_lds16(gA0 + (size_t)rowL * 768 + kt * 64,         &lds[bi][w * 1024]);
    gload_lds16(gB0 + (size_t)rowL * 768 + kt * 64,         &lds[bi][8192 + w * 1024]);
    gload_lds16(gB0 + (size_t)(rowL + 128) * 768 + kt * 64, &lds[bi][8192 + (w + 8) * 1024]);
  };

  auto COMPUTE = [&](int bi) {
    int4v af[4], bf8[4];
#pragma unroll
    for (int n = 0; n < 4; ++n)
      bf8[n] = *(const int4v*)(&lds[bi][b_off + n * 1024]);
#pragma unroll
    for (int m = 0; m < 4; ++m)
      af[m] = *(const int4v*)(&lds[bi][a_off + m * 1024]);
    __builtin_amdgcn_s_setprio(1);
#pragma unroll
    for (int m = 0; m < 4; ++m)
#pragma unroll
      for (int n = 0; n < 4; ++n)
        acc[m][n] = __builtin_amdgcn_mfma_i32_16x16x64_i8(af[m], bf8[n], acc[m][n], 0, 0, 0);
    __builtin_amdgcn_s_setprio(0);
  };

#define SB __builtin_amdgcn_sched_barrier(0)
#define BAR do { SB; __builtin_amdgcn_s_barrier(); SB; } while (0)

  // prologue: 2 K-tiles in flight (6 loads/thread)
  STAGE(0, 0); STAGE(1, 1);
  SB; asm volatile("s_waitcnt vmcnt(3)" ::: "memory");  // tile 0 landed
  BAR;

  for (int kt = 0; kt < 12; ++kt) {
    COMPUTE(kt & 1);
    BAR;                                  // all waves done reading buf kt&1
    if (kt < 10) {
      STAGE(kt & 1, kt + 2);              // refill freed buffer
      SB; asm volatile("s_waitcnt vmcnt(3)" ::: "memory");   // tile kt+1 landed (mine)
    } else if (kt == 10) {
      SB; asm volatile("s_waitcnt vmcnt(0)" ::: "memory");   // tile 11 landed
    }
    BAR;                                  // everyone's tile kt+1 landed
  }

  // epilogue: C/D layout col=lane&15, row=(lane>>4)*4+reg (dtype-independent).
  // Head-major dst: [which][b*8+h][tok][96]; dequant + exp fused for which==1.
  const int bb = brow / 1024;
#pragma unroll
  for (int m = 0; m < 4; ++m) {
    const int row0 = brow + wr * 64 + m * 16 + lhi * 4;
    const int tok0 = row0 & 1023;
    float ix[4];
#pragma unroll
    for (int r = 0; r < 4; ++r) ix[r] = inv_x[row0 + r];
#pragma unroll
    for (int n = 0; n < 4; ++n) {
      const int col   = bcol + wc * 64 + n * 16 + l15;
      const float dq0 = inv_w[col];
      const int which = col / 768;
      const int hh    = (col % 768) / 96;
      const int ch    = col % 96;
      unsigned short* dst = qkv + (size_t)which * WHICH_STRIDE
                          + ((size_t)(bb * 8 + hh)) * BH_STRIDE + ch;
#pragma unroll
      for (int r = 0; r < 4; ++r) {
        float v = (float)acc[m][n][r] * dq0 * ix[r];
        if (which == 1) v = __expf(v);
        dst[(size_t)(tok0 + r) * 96] = f2bf(v);
      }
    }
  }
#undef BAR
#undef SB
}

// ---------------- dd^T = (softmax(k)^T @ v)^T per (b,h) ------------------------
// k arrives PRE-EXP'd (fused in gemm epilogue) -> staging is pure u16 reorder.
// colsum via all-ones B-fragment MFMA; 2-region parallel reduce (waves 0-3/4-7).
__global__ __launch_bounds__(512, 2) void dd_fused(
    const unsigned short* __restrict__ qkv,
    unsigned short* __restrict__ ddT) {
  __shared__ __align__(16) char smem[124416];
  unsigned short* stg = (unsigned short*)smem;          // [8 waves][2][96*40]
  float* facc = (float*)smem;                           // alias: [2][96][100] fp32
  float* fsum = (float*)(smem + 122880);                // [2][96]
  float* sinv = (float*)(smem + 123648);                // [96]

  const int bh = blockIdx.x;
  const int t = threadIdx.x, w = t >> 6, l = t & 63;
  const int l15 = l & 15, lhi = l >> 4;

  unsigned short* myK = stg + w * 7680;
  unsigned short* myV = myK + 3840;
  const int n   = l >> 1;
  const int chh = l & 1;
  const unsigned short* kb = qkv + WHICH_STRIDE     + (size_t)bh * BH_STRIDE;
  const unsigned short* vb = qkv + 2 * WHICH_STRIDE + (size_t)bh * BH_STRIDE;

  f32x4 acc[6][6], accS[6];
#pragma unroll
  for (int mf = 0; mf < 6; ++mf) {
    accS[mf] = (f32x4){0.f, 0.f, 0.f, 0.f};
#pragma unroll
    for (int nf = 0; nf < 6; ++nf) acc[mf][nf] = (f32x4){0.f, 0.f, 0.f, 0.f};
  }
  short8 ones;
#pragma unroll
  for (int j = 0; j < 8; ++j) ones[j] = (short)0x3F80;   // bf16 1.0

  for (int tt = 0; tt < 4; ++tt) {
    const int n0 = w * 128 + tt * 32;
    const size_t g = (size_t)(n0 + n) * 96 + chh * 48;
#pragma unroll
    for (int i = 0; i < 6; ++i) {
      ushort8 k8 = *(const ushort8*)(kb + g + i * 8);
      ushort8 v8 = *(const ushort8*)(vb + g + i * 8);
      const int c0 = chh * 48 + i * 8;
#pragma unroll
      for (int j = 0; j < 8; ++j) {
        myK[(c0 + j) * 40 + n] = k8[j];
        myV[(c0 + j) * 40 + n] = v8[j];
      }
    }
    // same-wave DS ordering: compiler waits lgkmcnt before dependent reads
    short8 af[6], bf8[6];
#pragma unroll
    for (int mf = 0; mf < 6; ++mf)
      af[mf] = *(const short8*)((const char*)myK + (mf * 16 + l15) * 80 + lhi * 16);
#pragma unroll
    for (int nf = 0; nf < 6; ++nf)
      bf8[nf] = *(const short8*)((const char*)myV + (nf * 16 + l15) * 80 + lhi * 16);
#pragma unroll
    for (int mf = 0; mf < 6; ++mf) {
#pragma unroll
      for (int nf = 0; nf < 6; ++nf)
        acc[mf][nf] = __builtin_amdgcn_mfma_f32_16x16x32_bf16(af[mf], bf8[nf], acc[mf][nf], 0, 0, 0);
      accS[mf] = __builtin_amdgcn_mfma_f32_16x16x32_bf16(af[mf], ones, accS[mf], 0, 0, 0);
    }
  }

  __syncthreads();   // staging dead; facc aliases it
  float* fr  = facc + (w >> 2) * 9600;
  float* fsr = fsum + (w >> 2) * 96;
  for (int ww = 0; ww < 4; ++ww) {
    if ((w & 3) == ww) {
#pragma unroll
      for (int mf = 0; mf < 6; ++mf) {
#pragma unroll
        for (int nf = 0; nf < 6; ++nf) {
          const int c = mf * 16 + lhi * 4, d = nf * 16 + l15;
#pragma unroll
          for (int r = 0; r < 4; ++r) {
            float* p = fr + (size_t)(c + r) * 100 + d;
            if (ww == 0) *p = acc[mf][nf][r]; else *p += acc[mf][nf][r];
          }
        }
        if (l15 == 0) {
          const int c = mf * 16 + lhi * 4;
#pragma unroll
          for (int r = 0; r < 4; ++r) {
            if (ww == 0) fsr[c + r] = accS[mf][r];
            else         fsr[c + r] += accS[mf][r];
          }
        }
      }
    }
    __syncthreads();
  }
  // merge the two regions
  for (int i = t; i < 9600; i += 512) facc[i] += facc[9600 + i];
  if (t < 96) fsum[t] += fsum[96 + t];
  __syncthreads();
  if (t < 96) sinv[t] = 1.0f / fsum[t];
  __syncthreads();

  unsigned short* dst = ddT + (size_t)bh * 9216;
#pragma unroll
  for (int e = 0; e < 18; ++e) {
    const int idx = t * 18 + e;
    const int d = idx / 96, c = idx % 96;
    dst[idx] = f2bf(facc[(size_t)c * 100 + d] * sinv[c]);
  }
}

// ---------------- out = SCALE*(q@dd) + q*dwconv3x3(v), persistent over tokens --
// grid (2 halves, 8 h, 32 b), 256 thr, 4 waves 2x2 of (32 rows x 48 cols).
__global__ __launch_bounds__(256) void factor_conv_p(
    const unsigned short* __restrict__ qkv,
    const unsigned short* __restrict__ ddT,    // [bh][96 d][96 c] bf16
    const float* __restrict__ wcr,             // [768][9]
    const float* __restrict__ bcr,             // [768]
    float* __restrict__ outb) {
  __shared__ __align__(16) unsigned short sQ[64 * 96];    // 12288 B
  __shared__ __align__(16) unsigned short sD[96 * 96];    // 18432 B
  __shared__ __align__(16) unsigned short sV[128 * 96];   // 24576 B (v halo: 4 img rows)
  __shared__ float sW[96 * 9];
  __shared__ float sBias[96];
  const int half = blockIdx.x, h = blockIdx.y, b = blockIdx.z;
  const int t = threadIdx.x, wv = t >> 6, l = t & 63;
  const int l15 = l & 15, lhi = l >> 4;
  const int bh = b * 8 + h;

  // ---- stage ddT + weights once
  const char* dg = (const char*)ddT + (size_t)bh * 18432;
#pragma unroll
  for (int it = 0; it < 4; ++it)
    gload_lds16(dg + (it * 256 + t) * 16, (char*)sD + it * 4096 + wv * 1024);
  if (wv < 2)
    gload_lds16(dg + (1024 + t) * 16, (char*)sD + 16384 + wv * 1024);
  for (int i = t; i < 960; i += 256) {
    if (i < 864) sW[i] = wcr[(size_t)(h * 96) * 9 + i];
    else         sBias[i - 864] = bcr[h * 96 + (i - 864)];
  }

  const char* qg = (const char*)(qkv + (size_t)bh * BH_STRIDE);
  const char* vg = (const char*)(qkv + 2 * WHICH_STRIDE + (size_t)bh * BH_STRIDE);
  const int wrow = (wv >> 1) * 32;
  const int wcol = (wv & 1) * 48;

  for (int it8 = 0; it8 < 8; ++it8) {
    const int nt = half * 8 + it8;
    const int n0 = nt * 64, y0 = nt * 2;

    // ---- stage q tile (contiguous 12288 B)
#pragma unroll
    for (int it = 0; it < 3; ++it)
      gload_lds16(qg + (size_t)n0 * 192 + (it * 256 + t) * 16,
                  (char*)sQ + it * 4096 + wv * 1024);
    // ---- stage v halo (128 rows, clamped)
#pragma unroll
    for (int it = 0; it < 6; ++it) {
      const int f = it * 256 + t;
      const int row = f / 12, ch = f % 12;
      int tok = n0 - 32 + row;
      tok = tok < 0 ? 0 : (tok > 1023 ? 1023 : tok);
      gload_lds16(vg + (size_t)tok * 192 + ch * 16,
                  (char*)sV + it * 4096 + wv * 1024);
    }
    __syncthreads();   // drains vmcnt (incl. first-iter sD/weights)

    f32x4 acc[2][3];
#pragma unroll
    for (int m = 0; m < 2; ++m)
#pragma unroll
      for (int nn = 0; nn < 3; ++nn) acc[m][nn] = (f32x4){0.f, 0.f, 0.f, 0.f};

#pragma unroll
    for (int ks = 0; ks < 3; ++ks) {
      short8 af[2], bf8[3];
#pragma unroll
      for (int m = 0; m < 2; ++m)
        af[m] = *(const short8*)((const char*)sQ + (wrow + m*16 + l15) * 192 + ks * 64 + lhi * 16);
#pragma unroll
      for (int nn = 0; nn < 3; ++nn)
        bf8[nn] = *(const short8*)((const char*)sD + (wcol + nn*16 + l15) * 192 + ks * 64 + lhi * 16);
#pragma unroll
      for (int m = 0; m < 2; ++m)
#pragma unroll
        for (int nn = 0; nn < 3; ++nn)
          acc[m][nn] = __builtin_amdgcn_mfma_f32_16x16x32_bf16(af[m], bf8[nn], acc[m][nn], 0, 0, 0);
    }

    // epilogue: conv from sV, out = SCALE*acc + q*conv
#pragma unroll
    for (int nn = 0; nn < 3; ++nn) {
      const int dc = wcol + nn * 16 + l15;
      float w9[9];
#pragma unroll
      for (int k = 0; k < 9; ++k) w9[k] = sW[dc * 9 + k];
      const float bv = sBias[dc];
#pragma unroll
      for (int m = 0; m < 2; ++m) {
        const int rl0 = wrow + m * 16 + lhi * 4;     // 4 consecutive rows, same img y
        const int x = rl0 & 31, yl = rl0 >> 5;
        float cs[3][6];
#pragma unroll
        for (int dy = 0; dy < 3; ++dy) {
          const int gy = y0 + yl + dy - 1;
          const bool vy = (gy >= 0) && (gy < 32);
#pragma unroll
          for (int i = 0; i < 6; ++i) {
            const int xx = x - 1 + i;
            cs[dy][i] = (vy && xx >= 0 && xx < 32)
                ? bf2f(sV[((yl + dy) * 32 + xx) * 96 + dc]) : 0.f;
          }
        }
#pragma unroll
        for (int r = 0; r < 4; ++r) {
          float conv = bv;
#pragma unroll
          for (int dy = 0; dy < 3; ++dy)
#pragma unroll
            for (int dx = 0; dx < 3; ++dx)
              conv += w9[dy * 3 + dx] * cs[dy][r + dx];
          const int row = rl0 + r;
          const float qv = bf2f(sQ[row * 96 + dc]);
          outb[((size_t)(b * N_TOK + n0 + row)) * C_DIM + h * 96 + dc] =
              SCALE_F * acc[m][nn][r] + qv * conv;
        }
      }
    }
    __syncthreads();   // all sQ/sV readers done before next iter's stage
  }
}

extern "C" void kernel_launch(void* const* d_in, const int* in_sizes, int n_in,
                              void* d_out, int out_size, void* d_ws, size_t ws_size,
                              hipStream_t stream) {
  const float* x      = (const float*)d_in[0];
  const float* w_qkv  = (const float*)d_in[1];
  const float* w_crpe = (const float*)d_in[2];
  const float* b_crpe = (const float*)d_in[3];
  float* out = (float*)d_out;

  char* ws = (char*)d_ws;
  signed char*    xq    = (signed char*)ws;                             // 24 MB i8
  signed char*    wq    = (signed char*)(ws + 25165824);                // 1.7 MB i8
  float*          inv_x = (float*)(ws + 27000832);                      // 128 KB
  float*          inv_w = (float*)(ws + 27131904);                      // 9 KB
  unsigned short* qkv   = (unsigned short*)(ws + 53870592);             // 144 MB, [3][bh][n][96]
  unsigned short* ddT   = (unsigned short*)(ws + 204865536);            // 4.7 MB bf16

  quant_rows<<<dim3((GM + GN + 3) / 4), 256, 0, stream>>>(
      x, w_qkv, xq, wq, inv_x, inv_w);
  qkv_gemm_i8<<<dim3(2304), 512, 0, stream>>>(xq, wq, inv_x, inv_w, qkv);
  dd_fused<<<dim3(B_SZ * HEADS), 512, 0, stream>>>(qkv, ddT);
  factor_conv_p<<<dim3(2, HEADS, B_SZ), 256, 0, stream>>>(qkv, ddT, w_crpe, b_crpe, out);
}